// Round 11
// baseline (216.672 us; speedup 1.0000x reference)
//
#include <hip/hip_runtime.h>

#define B_ 8
#define NQ_ 2048
#define NK_ 2048
#define D_ 256
#define KF_ 1056   // folded DFT K (1025 live + pad), 33 steps of 32

typedef __attribute__((ext_vector_type(8))) short bf16x8_t;
typedef __attribute__((ext_vector_type(4))) float f32x4_t;

static __device__ __forceinline__ unsigned short f2bf(float x) {
  unsigned int u = __float_as_uint(x);
  unsigned int r = (u + 0x7FFFu + ((u >> 16) & 1u)) >> 16;
  return (unsigned short)r;
}
static __device__ __forceinline__ float bf2f(unsigned short b) {
  return __uint_as_float(((unsigned int)b) << 16);
}

typedef __attribute__((address_space(1))) unsigned int gas_u32;
typedef __attribute__((address_space(3))) unsigned int las_u32;
static __device__ __forceinline__ void gl16(const void* g, void* l) {
  __builtin_amdgcn_global_load_lds((const gas_u32*)g, (las_u32*)l, 16, 0, 0);
}

// ---------------------------------------------------------------------------
// generic f32 -> split bf16 (hi + lo)
// ---------------------------------------------------------------------------
__global__ __launch_bounds__(256) void split_kernel(const float* __restrict__ x,
                                                    unsigned short* __restrict__ xh,
                                                    unsigned short* __restrict__ xl,
                                                    int n) {
  const int i = blockIdx.x * 256 + threadIdx.x;
  if (i < n) {
    const float v = x[i];
    const unsigned short hb = f2bf(v);
    xh[i] = hb;
    xl[i] = f2bf(v - bf2f(hb));
  }
}

// C'[i][n] = cos(2*pi*(i*n mod 2048)/2048) for n<=1024, 0 for pad; split bf16
__global__ __launch_bounds__(256) void cos_split_kernel(unsigned short* __restrict__ Ch,
                                                        unsigned short* __restrict__ Cl) {
  const int idx = blockIdx.x * 256 + threadIdx.x;   // 1152*1056 total
  const int i = idx / KF_, n = idx % KF_;
  float c = 0.f;
  if (n <= 1024) {
    const int m = (i * n) & 2047;
    c = cosf((float)m * 0.0030679615757712823f);
  }
  const unsigned short hb = f2bf(c);
  Ch[idx] = hb;
  Cl[idx] = f2bf(c - bf2f(hb));
}

// Folded + transposed query: Qtf[b][d][n] = split(q[b][n][d] + q[b][2048-n][d])
// for n in 1..1023; n=0 -> q[0]; n=1024 -> q[1024]; n>=1025 -> 0.
__global__ __launch_bounds__(256) void qtf_split_kernel(const float* __restrict__ q,
                                                        unsigned short* __restrict__ Qtfh,
                                                        unsigned short* __restrict__ Qtfl) {
  __shared__ float lds[32][33];
  const int t  = threadIdx.x;
  const int n0 = blockIdx.x * 32;    // 33 tiles -> n up to 1055
  const int d0 = blockIdx.y * 32;
  const int b  = blockIdx.z;
#pragma unroll
  for (int p = 0; p < 4; ++p) {
    const int idx = t + 256 * p;
    const int dd = idx & 31, nn = idx >> 5;
    const int n = n0 + nn;
    float v = 0.f;
    if (n <= 1024) v = q[((size_t)b * NQ_ + n) * D_ + d0 + dd];
    if (n >= 1 && n <= 1023) v += q[((size_t)b * NQ_ + (2048 - n)) * D_ + d0 + dd];
    lds[nn][dd] = v;
  }
  __syncthreads();
#pragma unroll
  for (int p = 0; p < 4; ++p) {
    const int idx = t + 256 * p;
    const int nn = idx & 31, dd = idx >> 5;
    const float v = lds[nn][dd];
    const unsigned short hb = f2bf(v);
    const size_t o = ((size_t)b * D_ + d0 + dd) * KF_ + n0 + nn;
    Qtfh[o] = hb;
    Qtfl[o] = f2bf(v - bf2f(hb));
  }
}

// Vt[b][d][j] = keyh[b][j][d]
__global__ __launch_bounds__(256) void vt_bf16_kernel(const unsigned short* __restrict__ keyh,
                                                      unsigned short* __restrict__ Vt) {
  __shared__ unsigned short lds[32][40];
  const int t  = threadIdx.x;
  const int j0 = blockIdx.x * 32;
  const int d0 = blockIdx.y * 32;
  const int b  = blockIdx.z;
#pragma unroll
  for (int p = 0; p < 4; ++p) {
    const int idx = t + 256 * p;
    const int dd = idx & 31, jj = idx >> 5;
    lds[jj][dd] = keyh[((size_t)b * NK_ + j0 + jj) * D_ + d0 + dd];
  }
  __syncthreads();
#pragma unroll
  for (int p = 0; p < 4; ++p) {
    const int idx = t + 256 * p;
    const int jj = idx & 31, dd = idx >> 5;
    Vt[((size_t)b * D_ + d0 + dd) * NK_ + j0 + jj] = lds[jj][dd];
  }
}

// ---------------------------------------------------------------------------
// Folded DFT via split-bf16 3-MFMA. K = 1056, K-split=3 (352 = 11 steps of 32)
// with PRIVATE partial buffers + plain stores. (verified r8)
// ---------------------------------------------------------------------------
__global__ __launch_bounds__(256, 2) void dft_mfma(const unsigned short* __restrict__ Ch,
                                                   const unsigned short* __restrict__ Cl,
                                                   const unsigned short* __restrict__ Qtfh,
                                                   const unsigned short* __restrict__ Qtfl,
                                                   float* __restrict__ qr) {
  __shared__ __align__(16) unsigned short Ah[128][40];
  __shared__ __align__(16) unsigned short Al[128][40];
  __shared__ __align__(16) unsigned short Bh[128][40];
  __shared__ __align__(16) unsigned short Bl[128][40];
  const int t = threadIdx.x;
  const int b = blockIdx.z / 3, split = blockIdx.z % 3;
  const int i0 = blockIdx.x * 128, d0 = blockIdx.y * 128;
  const int w = t >> 6, lane = t & 63, quad = lane >> 4, l16 = lane & 15;
  const int wq = w & 1, wj = w >> 1;
  float* qrs = qr + (size_t)split * ((size_t)B_ * 1152 * D_);

  f32x4_t acc[4][4];
#pragma unroll
  for (int a = 0; a < 4; ++a)
#pragma unroll
    for (int c = 0; c < 4; ++c) acc[a][c] = (f32x4_t)0.f;

  const size_t abase = (size_t)i0 * KF_;
  const size_t bbase = ((size_t)b * D_ + d0) * KF_;

  for (int c0 = split * 352; c0 < split * 352 + 352; c0 += 32) {
#pragma unroll
    for (int it = 0; it < 2; ++it) {
      const int unit = t + 256 * it;           // 512 units = 128 rows x 4 slots
      const int row = unit >> 2, u = (unit & 3) * 8;
      const size_t go = (size_t)row * KF_ + c0 + u;
      *(uint4*)&Ah[row][u] = *(const uint4*)&Ch[abase + go];
      *(uint4*)&Al[row][u] = *(const uint4*)&Cl[abase + go];
      *(uint4*)&Bh[row][u] = *(const uint4*)&Qtfh[bbase + go];
      *(uint4*)&Bl[row][u] = *(const uint4*)&Qtfl[bbase + go];
    }
    __syncthreads();
    {
      const int dcol = quad * 8;
      bf16x8_t ah[4], al[4], bh[4], bl[4];
#pragma unroll
      for (int x = 0; x < 4; ++x) {
        ah[x] = *(const bf16x8_t*)&Ah[wq * 64 + x * 16 + l16][dcol];
        al[x] = *(const bf16x8_t*)&Al[wq * 64 + x * 16 + l16][dcol];
        bh[x] = *(const bf16x8_t*)&Bh[wj * 64 + x * 16 + l16][dcol];
        bl[x] = *(const bf16x8_t*)&Bl[wj * 64 + x * 16 + l16][dcol];
      }
#pragma unroll
      for (int at = 0; at < 4; ++at)
#pragma unroll
        for (int jt = 0; jt < 4; ++jt) {
          acc[at][jt] = __builtin_amdgcn_mfma_f32_16x16x32_bf16(ah[at], bh[jt], acc[at][jt], 0, 0, 0);
          acc[at][jt] = __builtin_amdgcn_mfma_f32_16x16x32_bf16(ah[at], bl[jt], acc[at][jt], 0, 0, 0);
          acc[at][jt] = __builtin_amdgcn_mfma_f32_16x16x32_bf16(al[at], bh[jt], acc[at][jt], 0, 0, 0);
        }
    }
    __syncthreads();
  }
#pragma unroll
  for (int at = 0; at < 4; ++at) {
#pragma unroll
    for (int jt = 0; jt < 4; ++jt) {
      const int d = d0 + wj * 64 + jt * 16 + l16;
#pragma unroll
      for (int r = 0; r < 4; ++r) {
        const int i = i0 + wq * 64 + at * 16 + quad * 4 + r;
        qrs[((size_t)b * 1152 + i) * D_ + d] = acc[at][jt][r];
      }
    }
  }
}

// qrh/qrl[b][i][d]: sum 3 partials; src = i<=1087 ? i : 2048-i
__global__ __launch_bounds__(256) void qr_finalize_kernel(const float* __restrict__ qr,
                                                          unsigned short* __restrict__ qrh,
                                                          unsigned short* __restrict__ qrl) {
  const int i = blockIdx.x, b = blockIdx.y, d = threadIdx.x;
  const int src = (i <= 1087) ? i : (2048 - i);
  const size_t S = (size_t)B_ * 1152 * D_;
  const size_t idx = ((size_t)b * 1152 + src) * D_ + d;
  const float v = qr[idx] + qr[idx + S] + qr[idx + 2 * S];
  const unsigned short hb = f2bf(v);
  const size_t o = ((size_t)b * NQ_ + i) * D_ + d;
  qrh[o] = hb;
  qrl[o] = f2bf(v - bf2f(hb));
}

// ---------------------------------------------------------------------------
// y = x @ W.T + bias -- split-bf16 3-MFMA, split epilogue (verified r3/r4)
// ---------------------------------------------------------------------------
__global__ __launch_bounds__(256, 2) void proj_mfma(const unsigned short* __restrict__ xh,
                                                    const unsigned short* __restrict__ xl,
                                                    const unsigned short* __restrict__ Wh,
                                                    const unsigned short* __restrict__ Wl,
                                                    const float* __restrict__ bias,
                                                    unsigned short* __restrict__ yh,
                                                    unsigned short* __restrict__ yl) {
  __shared__ __align__(16) unsigned short Xh[128][72];
  __shared__ __align__(16) unsigned short Xl[128][72];
  __shared__ __align__(16) unsigned short Bh[128][72];
  __shared__ __align__(16) unsigned short Bl[128][72];
  const int t = threadIdx.x;
  const int m0 = blockIdx.x * 128, o0 = blockIdx.y * 128;
  const int w = t >> 6, lane = t & 63, quad = lane >> 4, l16 = lane & 15;
  const int wq = w & 1, wj = w >> 1;

  f32x4_t acc[4][4];
#pragma unroll
  for (int a = 0; a < 4; ++a)
#pragma unroll
    for (int c = 0; c < 4; ++c) acc[a][c] = (f32x4_t)0.f;

  const size_t xbase = (size_t)m0 * D_;
  const size_t wbase = (size_t)o0 * D_;

  for (int c0 = 0; c0 < D_; c0 += 64) {
#pragma unroll
    for (int it = 0; it < 4; ++it) {
      const int unit = t + 256 * it;
      const int row = unit >> 3, u = (unit & 7) * 8;
      const size_t go = (size_t)row * D_ + c0 + u;
      *(uint4*)&Xh[row][u] = *(const uint4*)&xh[xbase + go];
      *(uint4*)&Xl[row][u] = *(const uint4*)&xl[xbase + go];
      *(uint4*)&Bh[row][u] = *(const uint4*)&Wh[wbase + go];
      *(uint4*)&Bl[row][u] = *(const uint4*)&Wl[wbase + go];
    }
    __syncthreads();
#pragma unroll
    for (int ks = 0; ks < 2; ++ks) {
      const int dcol = ks * 32 + quad * 8;
      bf16x8_t ah[4], al[4], bh[4], bl[4];
#pragma unroll
      for (int x = 0; x < 4; ++x) {
        ah[x] = *(const bf16x8_t*)&Xh[wq * 64 + x * 16 + l16][dcol];
        al[x] = *(const bf16x8_t*)&Xl[wq * 64 + x * 16 + l16][dcol];
        bh[x] = *(const bf16x8_t*)&Bh[wj * 64 + x * 16 + l16][dcol];
        bl[x] = *(const bf16x8_t*)&Bl[wj * 64 + x * 16 + l16][dcol];
      }
#pragma unroll
      for (int at = 0; at < 4; ++at)
#pragma unroll
        for (int jt = 0; jt < 4; ++jt) {
          acc[at][jt] = __builtin_amdgcn_mfma_f32_16x16x32_bf16(ah[at], bh[jt], acc[at][jt], 0, 0, 0);
          acc[at][jt] = __builtin_amdgcn_mfma_f32_16x16x32_bf16(ah[at], bl[jt], acc[at][jt], 0, 0, 0);
          acc[at][jt] = __builtin_amdgcn_mfma_f32_16x16x32_bf16(al[at], bh[jt], acc[at][jt], 0, 0, 0);
        }
    }
    __syncthreads();
  }
#pragma unroll
  for (int at = 0; at < 4; ++at) {
#pragma unroll
    for (int jt = 0; jt < 4; ++jt) {
      const int o = o0 + wj * 64 + jt * 16 + l16;
      const float bv = bias[o];
#pragma unroll
      for (int r = 0; r < 4; ++r) {
        const int m = m0 + wq * 64 + at * 16 + quad * 4 + r;
        const float v = acc[at][jt][r] + bv;
        const unsigned short hb = f2bf(v);
        yh[(size_t)m * D_ + o] = hb;
        yl[(size_t)m * D_ + o] = f2bf(v - bf2f(hb));
      }
    }
  }
}

// ---------------------------------------------------------------------------
// scores + per-jblock softmax stats -- pv_p-style DEEP PIPELINE:
// 128x128 tile, 8 waves (32x64 per wave, r7 decomposition), D-loop as 8
// chunks of 32, TRIPLE-buffered LDS (96KB, 1 block/CU), depth-2 prefetch,
// counted vmcnt(8). hi|lo packed rows + slot^(row&7) involution (r10).
// Pb TILED: Pb[(b*16+jb)][i][128]. ln2-grid offsets.
// ---------------------------------------------------------------------------
__global__ __launch_bounds__(512, 2) void scores_p(const unsigned short* __restrict__ qh,
                                                   const unsigned short* __restrict__ ql,
                                                   const unsigned short* __restrict__ kh,
                                                   const unsigned short* __restrict__ kl,
                                                   unsigned short* __restrict__ Pb,
                                                   float2* __restrict__ stat) {
  __shared__ __align__(16) unsigned short Qhl[3][128][64];   // [32 hi | 32 lo]
  __shared__ __align__(16) unsigned short Khl[3][128][64];
  __shared__ float mred[2][128];
  __shared__ float lred[2][128];
  const int t = threadIdx.x;
  const int b = blockIdx.z;
  const int i0 = blockIdx.x * 128, j0 = blockIdx.y * 128;
  const int jb = blockIdx.y;   // 0..15
  const int w = t >> 6, lane = t & 63, quad = lane >> 4, l16 = lane & 15;
  const int wq = w & 3, wj = w >> 2;         // 4 row-groups(32) x 2 col-groups(64)

  f32x4_t acc[2][4];
#pragma unroll
  for (int x = 0; x < 2; ++x)
#pragma unroll
    for (int y = 0; y < 4; ++y) acc[x][y] = (f32x4_t)0.f;

  const size_t qbase = ((size_t)b * NQ_ + i0) * D_;
  const size_t kbase = ((size_t)b * NK_ + j0) * D_;

  // stage one 32-wide D-chunk (Q 128 rows + K 128 rows, hi|lo packed) into
  // buffer nb: 4 gl16/thread. LDS linear dest; per-lane global source picks
  // array (hi/lo) + k-slot via involution lg = (lane&7)^(row&7); lg<4 = hi.
  auto STAGE = [&](int nb, int s) {
    const int c0 = s * 32;
#pragma unroll
    for (int cp = 0; cp < 2; ++cp) {         // Q rows w*16 .. +15
      const int r = w * 16 + cp * 8 + (lane >> 3);
      const int lg = (lane & 7) ^ (r & 7);
      const unsigned short* src = (lg < 4) ? qh : ql;
      gl16(src + qbase + (size_t)r * D_ + c0 + (lg & 3) * 8,
           &Qhl[nb][w * 16 + cp * 8][0]);
    }
#pragma unroll
    for (int cp = 0; cp < 2; ++cp) {         // K rows w*16 .. +15
      const int r = w * 16 + cp * 8 + (lane >> 3);
      const int lg = (lane & 7) ^ (r & 7);
      const unsigned short* src = (lg < 4) ? kh : kl;
      gl16(src + kbase + (size_t)r * D_ + c0 + (lg & 3) * 8,
           &Khl[nb][w * 16 + cp * 8][0]);
    }
  };

  STAGE(0, 0);
  STAGE(1, 1);

#pragma unroll
  for (int s = 0; s < 8; ++s) {
    const int cb = s % 3;
    if (s < 6) {
      STAGE((s + 2) % 3, s + 2);                        // depth-2 prefetch
      asm volatile("s_waitcnt vmcnt(8)" ::: "memory");  // chunk s ready
    } else if (s == 6) {
      asm volatile("s_waitcnt vmcnt(4)" ::: "memory");
    } else {
      asm volatile("s_waitcnt vmcnt(0)" ::: "memory");
    }
    __builtin_amdgcn_s_barrier();
    asm volatile("" ::: "memory");

    bf16x8_t ah[2], al[2], bh[4], bl[4];
#pragma unroll
    for (int x = 0; x < 2; ++x) {
      const int ar = wq * 32 + x * 16 + l16;
      ah[x] = *(const bf16x8_t*)&Qhl[cb][ar][(quad ^ (ar & 7)) * 8];
      al[x] = *(const bf16x8_t*)&Qhl[cb][ar][((4 + quad) ^ (ar & 7)) * 8];
    }
#pragma unroll
    for (int y = 0; y < 4; ++y) {
      const int br = wj * 64 + y * 16 + l16;
      bh[y] = *(const bf16x8_t*)&Khl[cb][br][(quad ^ (br & 7)) * 8];
      bl[y] = *(const bf16x8_t*)&Khl[cb][br][((4 + quad) ^ (br & 7)) * 8];
    }
#pragma unroll
    for (int x = 0; x < 2; ++x)
#pragma unroll
      for (int y = 0; y < 4; ++y) {
        acc[x][y] = __builtin_amdgcn_mfma_f32_16x16x32_bf16(ah[x], bh[y], acc[x][y], 0, 0, 0);
        acc[x][y] = __builtin_amdgcn_mfma_f32_16x16x32_bf16(ah[x], bl[y], acc[x][y], 0, 0, 0);
        acc[x][y] = __builtin_amdgcn_mfma_f32_16x16x32_bf16(al[x], bh[y], acc[x][y], 0, 0, 0);
      }

    asm volatile("" ::: "memory");
    __builtin_amdgcn_s_barrier();
    asm volatile("" ::: "memory");
  }

  // --- epilogue (verified r7): per-row max/exp/sum over 128 j, bf16 store
  const float scale = 0.0625f;
  float mt[2][4];
#pragma unroll
  for (int x = 0; x < 2; ++x)
#pragma unroll
    for (int r = 0; r < 4; ++r) mt[x][r] = -3e38f;
#pragma unroll
  for (int x = 0; x < 2; ++x)
#pragma unroll
    for (int y = 0; y < 4; ++y)
#pragma unroll
      for (int r = 0; r < 4; ++r) {
        acc[x][y][r] *= scale;
        mt[x][r] = fmaxf(mt[x][r], acc[x][y][r]);
      }
#pragma unroll
  for (int off = 1; off < 16; off <<= 1)
#pragma unroll
    for (int x = 0; x < 2; ++x)
#pragma unroll
      for (int r = 0; r < 4; ++r) mt[x][r] = fmaxf(mt[x][r], __shfl_xor(mt[x][r], off));
  if (l16 == 0) {
#pragma unroll
    for (int x = 0; x < 2; ++x)
#pragma unroll
      for (int r = 0; r < 4; ++r)
        mred[wj][wq * 32 + x * 16 + quad * 4 + r] = mt[x][r];
  }
  __syncthreads();
  float nrow[2][4], mu[2][4], lt[2][4];
#pragma unroll
  for (int x = 0; x < 2; ++x)
#pragma unroll
    for (int r = 0; r < 4; ++r) {
      const int rr = wq * 32 + x * 16 + quad * 4 + r;
      const float m = fmaxf(mred[0][rr], mred[1][rr]);
      const float n = ceilf(m * 1.44269504f);       // ln2 grid
      nrow[x][r] = n;
      mu[x][r] = n * 0.69314718056f;
      lt[x][r] = 0.f;
    }
  const size_t pbase = ((size_t)(b * 16 + jb)) * NQ_ * 128;
#pragma unroll
  for (int x = 0; x < 2; ++x)
#pragma unroll
    for (int y = 0; y < 4; ++y) {
      const int jloc = wj * 64 + y * 16 + l16;      // 0..127 within tile
#pragma unroll
      for (int r = 0; r < 4; ++r) {
        const int i = i0 + wq * 32 + x * 16 + quad * 4 + r;
        float p = __expf(acc[x][y][r] - mu[x][r]);
        p = fmaxf(p, 8.673617e-19f);                // clamp >= 2^-60 (no bf16 zeros)
        lt[x][r] += p;
        Pb[pbase + (size_t)i * 128 + jloc] = f2bf(p);
      }
    }
#pragma unroll
  for (int off = 1; off < 16; off <<= 1)
#pragma unroll
    for (int x = 0; x < 2; ++x)
#pragma unroll
      for (int r = 0; r < 4; ++r) lt[x][r] += __shfl_xor(lt[x][r], off);
  if (l16 == 0) {
#pragma unroll
    for (int x = 0; x < 2; ++x)
#pragma unroll
      for (int r = 0; r < 4; ++r)
        lred[wj][wq * 32 + x * 16 + quad * 4 + r] = lt[x][r];
  }
  __syncthreads();
  if (wj == 0 && l16 == 0) {
#pragma unroll
    for (int x = 0; x < 2; ++x)
#pragma unroll
      for (int r = 0; r < 4; ++r) {
        const int rr = wq * 32 + x * 16 + quad * 4 + r;
        stat[(size_t)jb * (B_ * NQ_) + (size_t)b * NQ_ + i0 + rr] =
            make_float2(nrow[x][r], lred[0][rr] + lred[1][rr]);
      }
  }
}

// ---------------------------------------------------------------------------
// per-row global stats from 16 jblock stats: srow = (n_max, 1/l)
// ---------------------------------------------------------------------------
__global__ __launch_bounds__(256) void rowfin_kernel(const float2* __restrict__ stat,
                                                     float2* __restrict__ srow) {
  const int i = blockIdx.x * 256 + threadIdx.x;   // 0..16383
  float2 st[16];
  float m = -3e38f;
#pragma unroll
  for (int jb = 0; jb < 16; ++jb) {
    st[jb] = stat[(size_t)jb * (B_ * NQ_) + i];
    m = fmaxf(m, st[jb].x);
  }
  float l = 0.f;
#pragma unroll
  for (int jb = 0; jb < 16; ++jb) l += st[jb].y * exp2f(st[jb].x - m);
  srow[i] = make_float2(m, 1.0f / l);
}

// ---------------------------------------------------------------------------
// out[m,d] = (1/l) * sum_{all j} P[m,j]*2^(n_jb-n_max) * V[j,d]
// ATOMIC-FREE (verified r6): each block owns 64 rows x ALL 2048 j -> plain
// stores. 256 blocks (1/CU), 512 threads, 64-wide j-steps, triple-buffered
// depth-2 gl16 pipeline (vmcnt(10)), XCD-remap for V L2 residency.
// ---------------------------------------------------------------------------
__global__ __launch_bounds__(512, 1) void pv_p(const unsigned short* __restrict__ Pb,
                                               const float2* __restrict__ stat,
                                               const float2* __restrict__ srow,
                                               const unsigned short* __restrict__ Vt,
                                               float* __restrict__ out) {
  __shared__ __align__(16) unsigned short Ps[3][64][64];
  __shared__ __align__(16) unsigned short Vs[3][256][64];
  const int t = threadIdx.x;
  const int lb = (blockIdx.x & 7) * 32 + (blockIdx.x >> 3);
  const int mb = lb * 64;                    // flattened row base (b*NQ + i)
  const int b  = lb >> 5;                    // batch (32 blocks per batch)
  const int i0 = mb & (NQ_ - 1);             // row within batch
  const int w = t >> 6, lane = t & 63, quad = lane >> 4, l16 = lane & 15;
  const int wm = w & 1, wd = w >> 1;         // wave: row-half (32), d-quarter (64)
  const int prow = t >> 3, pslot = t & 7;    // staging: row, 16B slot

  unsigned int es2[16][2];
  {
    float nmax[2];
#pragma unroll
    for (int x = 0; x < 2; ++x)
      nmax[x] = srow[mb + wm * 32 + x * 16 + l16].x;
#pragma unroll
    for (int jb = 0; jb < 16; ++jb)
#pragma unroll
      for (int x = 0; x < 2; ++x) {
        const int arow = mb + wm * 32 + x * 16 + l16;
        int e = (int)(nmax[x] - stat[(size_t)jb * (B_ * NQ_) + arow].x);
        e = e < 0 ? 0 : (e > 60 ? 60 : e);
        es2[jb][x] = (unsigned int)(e << 7) * 0x00010001u;
      }
  }

  f32x4_t acc[2][4];
#pragma unroll
  for (int x = 0; x < 2; ++x)
#pragma unroll
    for (int y = 0; y < 4; ++y) acc[x][y] = (f32x4_t)0.f;

  const size_t vbase = (size_t)b * D_ * (size_t)NK_;

  auto STAGE = [&](int nb, int s) {
    const int jj = s * 64;
    const int jb = jj >> 7, off = jj & 127;
    {  // P: 1 gl16/thread
      const int sg = pslot ^ (prow & 7);
      gl16(Pb + ((size_t)(b * 16 + jb)) * NQ_ * 128 +
               (size_t)(i0 + prow) * 128 + off + sg * 8,
           &Ps[nb][w * 8][0]);
    }
#pragma unroll
    for (int k = 0; k < 4; ++k) {  // V: 4 gl16/thread
      const int vrow = k * 64 + prow;
      const int sg = pslot ^ (vrow & 7);
      gl16(Vt + vbase + (size_t)vrow * NK_ + jj + sg * 8,
           &Vs[nb][k * 64 + w * 8][0]);
    }
  };

  asm volatile("s_waitcnt vmcnt(0)" ::: "memory");  // drain stat/srow loads
  STAGE(0, 0);
  STAGE(1, 1);

#pragma unroll
  for (int s = 0; s < 32; ++s) {
    const int cb = s % 3;
    if (s < 30) {
      STAGE((s + 2) % 3, s + 2);                        // depth-2 prefetch
      asm volatile("s_waitcnt vmcnt(10)" ::: "memory"); // step s ready
    } else if (s == 30) {
      asm volatile("s_waitcnt vmcnt(5)" ::: "memory");
    } else {
      asm volatile("s_waitcnt vmcnt(0)" ::: "memory");
    }
    __builtin_amdgcn_s_barrier();
    asm volatile("" ::: "memory");

    const unsigned int e0 = es2[s >> 1][0], e1 = es2[s >> 1][1];
#pragma unroll
    for (int ks = 0; ks < 2; ++ks) {
      bf16x8_t a[2], bv[4];
#pragma unroll
      for (int x = 0; x < 2; ++x) {
        const int row = wm * 32 + x * 16 + l16;
        const int sk = (ks * 4 + quad) ^ (row & 7);
        uint4 u = *(const uint4*)&Ps[cb][row][sk * 8];
        const unsigned int e = (x == 0) ? e0 : e1;
        u.x -= e; u.y -= e; u.z -= e; u.w -= e;
        a[x] = *(const bf16x8_t*)&u;                 // P * 2^(n_jb - n_max)
      }
#pragma unroll
      for (int y = 0; y < 4; ++y) {
        const int row = wd * 64 + y * 16 + l16;
        const int sk = (ks * 4 + quad) ^ (row & 7);
        bv[y] = *(const bf16x8_t*)&Vs[cb][row][sk * 8];
      }
#pragma unroll
      for (int x = 0; x < 2; ++x)
#pragma unroll
        for (int y = 0; y < 4; ++y)
          acc[x][y] = __builtin_amdgcn_mfma_f32_16x16x32_bf16(a[x], bv[y], acc[x][y], 0, 0, 0);
    }

    asm volatile("" ::: "memory");
    __builtin_amdgcn_s_barrier();
    asm volatile("" ::: "memory");
  }

#pragma unroll
  for (int x = 0; x < 2; ++x) {
    float sy[4];
#pragma unroll
    for (int r = 0; r < 4; ++r)
      sy[r] = srow[mb + wm * 32 + x * 16 + quad * 4 + r].y;
#pragma unroll
    for (int y = 0; y < 4; ++y) {
      const int d = wd * 64 + y * 16 + l16;
#pragma unroll
      for (int r = 0; r < 4; ++r) {
        const int m = mb + wm * 32 + x * 16 + quad * 4 + r;
        out[(size_t)m * D_ + d] = acc[x][y][r] * sy[r];
      }
    }
  }
}

extern "C" void kernel_launch(void* const* d_in, const int* in_sizes, int n_in,
                              void* d_out, int out_size, void* d_ws, size_t ws_size,
                              hipStream_t stream) {
  const float* query = (const float*)d_in[0];
  const float* key   = (const float*)d_in[1];
  const float* Wq    = (const float*)d_in[2];
  const float* bq    = (const float*)d_in[3];
  const float* Wk    = (const float*)d_in[4];
  const float* bk    = (const float*)d_in[5];
  float* out = (float*)d_out;

  char* ws = (char*)d_ws;
  const size_t MB = (size_t)1 << 20;
  // persistent:
  unsigned short* qh = (unsigned short*)(ws);             // 8 MB
  unsigned short* ql = (unsigned short*)(ws + 8 * MB);
  unsigned short* kh = (unsigned short*)(ws + 16 * MB);
  unsigned short* kl = (unsigned short*)(ws + 24 * MB);
  unsigned short* Vt = (unsigned short*)(ws + 32 * MB);
  unsigned short* Pb = (unsigned short*)(ws + 40 * MB);   // 64 MB (tiled [b*16+jb][2048][128])
  float2* stat = (float2*)(ws + 108 * MB);                // 2 MB
  float2* srow = (float2*)(ws + 110 * MB);                // 128 KB
  // transients (all dead before scores_p writes Pb):
  unsigned short* Ch   = (unsigned short*)(ws + 40 * MB);   // 2.43 MB (1152x1056)
  unsigned short* Cl   = (unsigned short*)(ws + 43 * MB);   // 2.43 MB
  unsigned short* Qtfh = (unsigned short*)(ws + 46 * MB);   // 4.33 MB (8x256x1056)
  unsigned short* Qtfl = (unsigned short*)(ws + 51 * MB);   // 4.33 MB
  float*          qr   = (float*)(ws + 56 * MB);            // 3 x 9.44 MB partials (56,66,76)
  unsigned short* qrh  = (unsigned short*)(ws + 40 * MB);   // 8 MB (overlays dead C'/Qtf)
  unsigned short* qrl  = (unsigned short*)(ws + 48 * MB);   // 8 MB (ends 56, before qr partials)
  unsigned short* keyh = (unsigned short*)(ws + 92 * MB);   // 8 MB
  unsigned short* keyl = (unsigned short*)(ws + 100 * MB);  // 8 MB
  unsigned short* Wqh  = (unsigned short*)(ws + 111 * MB);  // 128 KB
  unsigned short* Wql  = (unsigned short*)(ws + 111 * MB + 256 * 1024);
  unsigned short* Wkh  = (unsigned short*)(ws + 111 * MB + 512 * 1024);
  unsigned short* Wkl  = (unsigned short*)(ws + 111 * MB + 768 * 1024);

  dim3 blk(256);

  split_kernel<<<B_ * NK_ * D_ / 256, blk, 0, stream>>>(key, keyh, keyl, B_ * NK_ * D_);
  split_kernel<<<D_ * D_ / 256, blk, 0, stream>>>(Wq, Wqh, Wql, D_ * D_);
  split_kernel<<<D_ * D_ / 256, blk, 0, stream>>>(Wk, Wkh, Wkl, D_ * D_);
  cos_split_kernel<<<1152 * KF_ / 256, blk, 0, stream>>>(Ch, Cl);
  qtf_split_kernel<<<dim3(KF_ / 32, D_ / 32, B_), blk, 0, stream>>>(query, Qtfh, Qtfl);
  // folded DFT: K=1056, 3-way K-split into private partial buffers
  dft_mfma<<<dim3(9, 2, B_ * 3), blk, 0, stream>>>(Ch, Cl, Qtfh, Qtfl, qr);
  qr_finalize_kernel<<<dim3(2048, B_), blk, 0, stream>>>(qr, qrh, qrl);
  // projections
  proj_mfma<<<dim3(B_ * NQ_ / 128, 2), blk, 0, stream>>>(qrh, qrl, Wqh, Wql, bq, qh, ql);
  proj_mfma<<<dim3(B_ * NK_ / 128, 2), blk, 0, stream>>>(keyh, keyl, Wkh, Wkl, bk, kh, kl);
  vt_bf16_kernel<<<dim3(NK_ / 32, D_ / 32, B_), blk, 0, stream>>>(keyh, Vt);
  // attention: scores (deep-pipeline, bf16 P + per-jb pow2 stats) -> PV
  scores_p<<<dim3(NQ_ / 128, NK_ / 128, B_), dim3(512), 0, stream>>>(qh, ql, kh, kl, Pb, stat);
  rowfin_kernel<<<B_ * NQ_ / 256, blk, 0, stream>>>(stat, srow);
  pv_p<<<dim3(256), dim3(512), 0, stream>>>(Pb, stat, srow, Vt, out);
}

// Round 12
// 201.119 us; speedup vs baseline: 1.0773x; 1.0773x over previous
//
#include <hip/hip_runtime.h>

#define B_ 8
#define NQ_ 2048
#define NK_ 2048
#define D_ 256
#define KF_ 1056   // folded DFT K (1025 live + pad), 33 steps of 32

typedef __attribute__((ext_vector_type(8))) short bf16x8_t;
typedef __attribute__((ext_vector_type(4))) float f32x4_t;

static __device__ __forceinline__ unsigned short f2bf(float x) {
  unsigned int u = __float_as_uint(x);
  unsigned int r = (u + 0x7FFFu + ((u >> 16) & 1u)) >> 16;
  return (unsigned short)r;
}
static __device__ __forceinline__ float bf2f(unsigned short b) {
  return __uint_as_float(((unsigned int)b) << 16);
}

typedef __attribute__((address_space(1))) unsigned int gas_u32;
typedef __attribute__((address_space(3))) unsigned int las_u32;
static __device__ __forceinline__ void gl16(const void* g, void* l) {
  __builtin_amdgcn_global_load_lds((const gas_u32*)g, (las_u32*)l, 16, 0, 0);
}

// ---------------------------------------------------------------------------
// generic f32 -> split bf16 (hi + lo)
// ---------------------------------------------------------------------------
__global__ __launch_bounds__(256) void split_kernel(const float* __restrict__ x,
                                                    unsigned short* __restrict__ xh,
                                                    unsigned short* __restrict__ xl,
                                                    int n) {
  const int i = blockIdx.x * 256 + threadIdx.x;
  if (i < n) {
    const float v = x[i];
    const unsigned short hb = f2bf(v);
    xh[i] = hb;
    xl[i] = f2bf(v - bf2f(hb));
  }
}

// Fused: key f32 -> keyh/keyl (split bf16, coalesced row writes) AND
// Vt[b][d][j] = keyh (transposed via LDS). One 16MB read instead of
// 16MB read + 8MB re-read; one launch instead of two.
__global__ __launch_bounds__(256) void key_split_vt(const float* __restrict__ key,
                                                    unsigned short* __restrict__ keyh,
                                                    unsigned short* __restrict__ keyl,
                                                    unsigned short* __restrict__ Vt) {
  __shared__ unsigned short lds[32][258];   // 129-dword row stride: conflict-free transpose
  const int t = threadIdx.x;
  const int j0 = blockIdx.x * 32;
  const int b  = blockIdx.y;
  // phase 1: 32 full rows; thread t owns column d=t of every row
#pragma unroll
  for (int p = 0; p < 32; ++p) {
    const size_t g = ((size_t)b * NK_ + j0 + p) * D_ + t;
    const float v = key[g];
    const unsigned short hb = f2bf(v);
    keyh[g] = hb;
    keyl[g] = f2bf(v - bf2f(hb));
    lds[p][t] = hb;
  }
  __syncthreads();
  // phase 2: transpose out: thread t -> jj = t&31, d = (t>>5) + 8*p
#pragma unroll
  for (int p = 0; p < 32; ++p) {
    const int jj = t & 31;
    const int d  = (t >> 5) + 8 * p;
    Vt[((size_t)b * D_ + d) * NK_ + j0 + jj] = lds[jj][d];
  }
}

// C'[i][n] = cos(2*pi*(i*n mod 2048)/2048) for n<=1024, 0 for pad; split bf16
__global__ __launch_bounds__(256) void cos_split_kernel(unsigned short* __restrict__ Ch,
                                                        unsigned short* __restrict__ Cl) {
  const int idx = blockIdx.x * 256 + threadIdx.x;   // 1152*1056 total
  const int i = idx / KF_, n = idx % KF_;
  float c = 0.f;
  if (n <= 1024) {
    const int m = (i * n) & 2047;
    c = cosf((float)m * 0.0030679615757712823f);
  }
  const unsigned short hb = f2bf(c);
  Ch[idx] = hb;
  Cl[idx] = f2bf(c - bf2f(hb));
}

// Folded + transposed query: Qtf[b][d][n] = split(q[b][n][d] + q[b][2048-n][d])
// for n in 1..1023; n=0 -> q[0]; n=1024 -> q[1024]; n>=1025 -> 0.
__global__ __launch_bounds__(256) void qtf_split_kernel(const float* __restrict__ q,
                                                        unsigned short* __restrict__ Qtfh,
                                                        unsigned short* __restrict__ Qtfl) {
  __shared__ float lds[32][33];
  const int t  = threadIdx.x;
  const int n0 = blockIdx.x * 32;    // 33 tiles -> n up to 1055
  const int d0 = blockIdx.y * 32;
  const int b  = blockIdx.z;
#pragma unroll
  for (int p = 0; p < 4; ++p) {
    const int idx = t + 256 * p;
    const int dd = idx & 31, nn = idx >> 5;
    const int n = n0 + nn;
    float v = 0.f;
    if (n <= 1024) v = q[((size_t)b * NQ_ + n) * D_ + d0 + dd];
    if (n >= 1 && n <= 1023) v += q[((size_t)b * NQ_ + (2048 - n)) * D_ + d0 + dd];
    lds[nn][dd] = v;
  }
  __syncthreads();
#pragma unroll
  for (int p = 0; p < 4; ++p) {
    const int idx = t + 256 * p;
    const int nn = idx & 31, dd = idx >> 5;
    const float v = lds[nn][dd];
    const unsigned short hb = f2bf(v);
    const size_t o = ((size_t)b * D_ + d0 + dd) * KF_ + n0 + nn;
    Qtfh[o] = hb;
    Qtfl[o] = f2bf(v - bf2f(hb));
  }
}

// ---------------------------------------------------------------------------
// Folded DFT via split-bf16 3-MFMA. K = 1056, K-split=3 (352 = 11 steps of 32)
// with PRIVATE partial buffers + plain stores. (verified r8)
// ---------------------------------------------------------------------------
__global__ __launch_bounds__(256, 2) void dft_mfma(const unsigned short* __restrict__ Ch,
                                                   const unsigned short* __restrict__ Cl,
                                                   const unsigned short* __restrict__ Qtfh,
                                                   const unsigned short* __restrict__ Qtfl,
                                                   float* __restrict__ qr) {
  __shared__ __align__(16) unsigned short Ah[128][40];
  __shared__ __align__(16) unsigned short Al[128][40];
  __shared__ __align__(16) unsigned short Bh[128][40];
  __shared__ __align__(16) unsigned short Bl[128][40];
  const int t = threadIdx.x;
  const int b = blockIdx.z / 3, split = blockIdx.z % 3;
  const int i0 = blockIdx.x * 128, d0 = blockIdx.y * 128;
  const int w = t >> 6, lane = t & 63, quad = lane >> 4, l16 = lane & 15;
  const int wq = w & 1, wj = w >> 1;
  float* qrs = qr + (size_t)split * ((size_t)B_ * 1152 * D_);

  f32x4_t acc[4][4];
#pragma unroll
  for (int a = 0; a < 4; ++a)
#pragma unroll
    for (int c = 0; c < 4; ++c) acc[a][c] = (f32x4_t)0.f;

  const size_t abase = (size_t)i0 * KF_;
  const size_t bbase = ((size_t)b * D_ + d0) * KF_;

  for (int c0 = split * 352; c0 < split * 352 + 352; c0 += 32) {
#pragma unroll
    for (int it = 0; it < 2; ++it) {
      const int unit = t + 256 * it;           // 512 units = 128 rows x 4 slots
      const int row = unit >> 2, u = (unit & 3) * 8;
      const size_t go = (size_t)row * KF_ + c0 + u;
      *(uint4*)&Ah[row][u] = *(const uint4*)&Ch[abase + go];
      *(uint4*)&Al[row][u] = *(const uint4*)&Cl[abase + go];
      *(uint4*)&Bh[row][u] = *(const uint4*)&Qtfh[bbase + go];
      *(uint4*)&Bl[row][u] = *(const uint4*)&Qtfl[bbase + go];
    }
    __syncthreads();
    {
      const int dcol = quad * 8;
      bf16x8_t ah[4], al[4], bh[4], bl[4];
#pragma unroll
      for (int x = 0; x < 4; ++x) {
        ah[x] = *(const bf16x8_t*)&Ah[wq * 64 + x * 16 + l16][dcol];
        al[x] = *(const bf16x8_t*)&Al[wq * 64 + x * 16 + l16][dcol];
        bh[x] = *(const bf16x8_t*)&Bh[wj * 64 + x * 16 + l16][dcol];
        bl[x] = *(const bf16x8_t*)&Bl[wj * 64 + x * 16 + l16][dcol];
      }
#pragma unroll
      for (int at = 0; at < 4; ++at)
#pragma unroll
        for (int jt = 0; jt < 4; ++jt) {
          acc[at][jt] = __builtin_amdgcn_mfma_f32_16x16x32_bf16(ah[at], bh[jt], acc[at][jt], 0, 0, 0);
          acc[at][jt] = __builtin_amdgcn_mfma_f32_16x16x32_bf16(ah[at], bl[jt], acc[at][jt], 0, 0, 0);
          acc[at][jt] = __builtin_amdgcn_mfma_f32_16x16x32_bf16(al[at], bh[jt], acc[at][jt], 0, 0, 0);
        }
    }
    __syncthreads();
  }
#pragma unroll
  for (int at = 0; at < 4; ++at) {
#pragma unroll
    for (int jt = 0; jt < 4; ++jt) {
      const int d = d0 + wj * 64 + jt * 16 + l16;
#pragma unroll
      for (int r = 0; r < 4; ++r) {
        const int i = i0 + wq * 64 + at * 16 + quad * 4 + r;
        qrs[((size_t)b * 1152 + i) * D_ + d] = acc[at][jt][r];
      }
    }
  }
}

// qrh/qrl[b][i][d]: sum 3 partials; src = i<=1087 ? i : 2048-i
__global__ __launch_bounds__(256) void qr_finalize_kernel(const float* __restrict__ qr,
                                                          unsigned short* __restrict__ qrh,
                                                          unsigned short* __restrict__ qrl) {
  const int i = blockIdx.x, b = blockIdx.y, d = threadIdx.x;
  const int src = (i <= 1087) ? i : (2048 - i);
  const size_t S = (size_t)B_ * 1152 * D_;
  const size_t idx = ((size_t)b * 1152 + src) * D_ + d;
  const float v = qr[idx] + qr[idx + S] + qr[idx + 2 * S];
  const unsigned short hb = f2bf(v);
  const size_t o = ((size_t)b * NQ_ + i) * D_ + d;
  qrh[o] = hb;
  qrl[o] = f2bf(v - bf2f(hb));
}

// ---------------------------------------------------------------------------
// y = x @ W.T + bias -- split-bf16 3-MFMA, split epilogue (verified r3/r4)
// ---------------------------------------------------------------------------
__global__ __launch_bounds__(256, 2) void proj_mfma(const unsigned short* __restrict__ xh,
                                                    const unsigned short* __restrict__ xl,
                                                    const unsigned short* __restrict__ Wh,
                                                    const unsigned short* __restrict__ Wl,
                                                    const float* __restrict__ bias,
                                                    unsigned short* __restrict__ yh,
                                                    unsigned short* __restrict__ yl) {
  __shared__ __align__(16) unsigned short Xh[128][72];
  __shared__ __align__(16) unsigned short Xl[128][72];
  __shared__ __align__(16) unsigned short Bh[128][72];
  __shared__ __align__(16) unsigned short Bl[128][72];
  const int t = threadIdx.x;
  const int m0 = blockIdx.x * 128, o0 = blockIdx.y * 128;
  const int w = t >> 6, lane = t & 63, quad = lane >> 4, l16 = lane & 15;
  const int wq = w & 1, wj = w >> 1;

  f32x4_t acc[4][4];
#pragma unroll
  for (int a = 0; a < 4; ++a)
#pragma unroll
    for (int c = 0; c < 4; ++c) acc[a][c] = (f32x4_t)0.f;

  const size_t xbase = (size_t)m0 * D_;
  const size_t wbase = (size_t)o0 * D_;

  for (int c0 = 0; c0 < D_; c0 += 64) {
#pragma unroll
    for (int it = 0; it < 4; ++it) {
      const int unit = t + 256 * it;
      const int row = unit >> 3, u = (unit & 7) * 8;
      const size_t go = (size_t)row * D_ + c0 + u;
      *(uint4*)&Xh[row][u] = *(const uint4*)&xh[xbase + go];
      *(uint4*)&Xl[row][u] = *(const uint4*)&xl[xbase + go];
      *(uint4*)&Bh[row][u] = *(const uint4*)&Wh[wbase + go];
      *(uint4*)&Bl[row][u] = *(const uint4*)&Wl[wbase + go];
    }
    __syncthreads();
#pragma unroll
    for (int ks = 0; ks < 2; ++ks) {
      const int dcol = ks * 32 + quad * 8;
      bf16x8_t ah[4], al[4], bh[4], bl[4];
#pragma unroll
      for (int x = 0; x < 4; ++x) {
        ah[x] = *(const bf16x8_t*)&Xh[wq * 64 + x * 16 + l16][dcol];
        al[x] = *(const bf16x8_t*)&Xl[wq * 64 + x * 16 + l16][dcol];
        bh[x] = *(const bf16x8_t*)&Bh[wj * 64 + x * 16 + l16][dcol];
        bl[x] = *(const bf16x8_t*)&Bl[wj * 64 + x * 16 + l16][dcol];
      }
#pragma unroll
      for (int at = 0; at < 4; ++at)
#pragma unroll
        for (int jt = 0; jt < 4; ++jt) {
          acc[at][jt] = __builtin_amdgcn_mfma_f32_16x16x32_bf16(ah[at], bh[jt], acc[at][jt], 0, 0, 0);
          acc[at][jt] = __builtin_amdgcn_mfma_f32_16x16x32_bf16(ah[at], bl[jt], acc[at][jt], 0, 0, 0);
          acc[at][jt] = __builtin_amdgcn_mfma_f32_16x16x32_bf16(al[at], bh[jt], acc[at][jt], 0, 0, 0);
        }
    }
    __syncthreads();
  }
#pragma unroll
  for (int at = 0; at < 4; ++at) {
#pragma unroll
    for (int jt = 0; jt < 4; ++jt) {
      const int o = o0 + wj * 64 + jt * 16 + l16;
      const float bv = bias[o];
#pragma unroll
      for (int r = 0; r < 4; ++r) {
        const int m = m0 + wq * 64 + at * 16 + quad * 4 + r;
        const float v = acc[at][jt][r] + bv;
        const unsigned short hb = f2bf(v);
        yh[(size_t)m * D_ + o] = hb;
        yl[(size_t)m * D_ + o] = f2bf(v - bf2f(hb));
      }
    }
  }
}

// ---------------------------------------------------------------------------
// scores + per-jblock softmax stats. 8-wave, BK=64 SINGLE-BUFFER m97-style
// (verified r9): step = { vmcnt(0) -> barrier -> ds_read + MFMA -> barrier ->
// stage next (8 gl16/thread) }. 66KB LDS keeps 2 blocks/CU (16 waves).
// XOR swizzle: slot ^ (row&7). Pb TILED: Pb[(b*16+jb)][i][128]. ln2 offsets.
// ---------------------------------------------------------------------------
__global__ __launch_bounds__(512, 4) void scores_p(const unsigned short* __restrict__ qh,
                                                   const unsigned short* __restrict__ ql,
                                                   const unsigned short* __restrict__ kh,
                                                   const unsigned short* __restrict__ kl,
                                                   unsigned short* __restrict__ Pb,
                                                   float2* __restrict__ stat) {
  __shared__ __align__(16) unsigned short Qh[128][64];
  __shared__ __align__(16) unsigned short Ql[128][64];
  __shared__ __align__(16) unsigned short Kh[128][64];
  __shared__ __align__(16) unsigned short Kl[128][64];
  __shared__ float mred[2][128];
  __shared__ float lred[2][128];
  const int t = threadIdx.x;
  const int b = blockIdx.z;
  const int i0 = blockIdx.x * 128, j0 = blockIdx.y * 128;
  const int jb = blockIdx.y;   // 0..15
  const int w = t >> 6, lane = t & 63, quad = lane >> 4, l16 = lane & 15;
  const int wq = w & 3, wj = w >> 2;         // 4 row-groups x 2 col-groups
  const int sr0 = t >> 3, ssl = t & 7;       // staging: row 0..63, 16B slot 0..7

  f32x4_t acc[2][4];
#pragma unroll
  for (int x = 0; x < 2; ++x)
#pragma unroll
    for (int y = 0; y < 4; ++y) acc[x][y] = (f32x4_t)0.f;

  const size_t qbase = ((size_t)b * NQ_ + i0) * D_;
  const size_t kbase = ((size_t)b * NK_ + j0) * D_;

  // stage one 64-wide K-step: 8 gl16/thread. LDS linear (dest row = wave's
  // 8-row chunk); global source slot XOR-swizzled (slot ^ (row&7)) so the
  // ds_read_b128 fragment reads are conflict-free (2-way max).
  auto STAGE = [&](int c0) {
#pragma unroll
    for (int half = 0; half < 2; ++half) {
      const int row = half * 64 + sr0;
      const int sg = (ssl ^ (row & 7)) * 8;
      const size_t ro = (size_t)row * D_ + c0 + sg;
      gl16(qh + qbase + ro, &Qh[half * 64 + w * 8][0]);
      gl16(ql + qbase + ro, &Ql[half * 64 + w * 8][0]);
      gl16(kh + kbase + ro, &Kh[half * 64 + w * 8][0]);
      gl16(kl + kbase + ro, &Kl[half * 64 + w * 8][0]);
    }
  };

  STAGE(0);   // prologue

#pragma unroll
  for (int s = 0; s < 4; ++s) {
    asm volatile("s_waitcnt vmcnt(0)" ::: "memory");   // tile s staged
    __builtin_amdgcn_s_barrier();
    asm volatile("" ::: "memory");

#pragma unroll
    for (int ks = 0; ks < 2; ++ks) {
      bf16x8_t ah[2], al[2], bh[4], bl[4];
#pragma unroll
      for (int x = 0; x < 2; ++x) {
        const int ar = wq * 32 + x * 16 + l16;
        const int asl = ((ks * 4 + quad) ^ (ar & 7)) * 8;
        ah[x] = *(const bf16x8_t*)&Qh[ar][asl];
        al[x] = *(const bf16x8_t*)&Ql[ar][asl];
      }
#pragma unroll
      for (int y = 0; y < 4; ++y) {
        const int br = wj * 64 + y * 16 + l16;
        const int bsl = ((ks * 4 + quad) ^ (br & 7)) * 8;
        bh[y] = *(const bf16x8_t*)&Kh[br][bsl];
        bl[y] = *(const bf16x8_t*)&Kl[br][bsl];
      }
#pragma unroll
      for (int x = 0; x < 2; ++x)
#pragma unroll
        for (int y = 0; y < 4; ++y) {
          acc[x][y] = __builtin_amdgcn_mfma_f32_16x16x32_bf16(ah[x], bh[y], acc[x][y], 0, 0, 0);
          acc[x][y] = __builtin_amdgcn_mfma_f32_16x16x32_bf16(ah[x], bl[y], acc[x][y], 0, 0, 0);
          acc[x][y] = __builtin_amdgcn_mfma_f32_16x16x32_bf16(al[x], bh[y], acc[x][y], 0, 0, 0);
        }
    }

    asm volatile("" ::: "memory");
    __builtin_amdgcn_s_barrier();
    asm volatile("" ::: "memory");
    if (s < 3) STAGE((s + 1) * 64);                    // overwrite buffer
  }

  // --- epilogue: per-row (over this block's 128 j) max, exp, sum, bf16 store
  const float scale = 0.0625f;
  float mt[2][4];
#pragma unroll
  for (int x = 0; x < 2; ++x)
#pragma unroll
    for (int r = 0; r < 4; ++r) mt[x][r] = -3e38f;
#pragma unroll
  for (int x = 0; x < 2; ++x)
#pragma unroll
    for (int y = 0; y < 4; ++y)
#pragma unroll
      for (int r = 0; r < 4; ++r) {
        acc[x][y][r] *= scale;
        mt[x][r] = fmaxf(mt[x][r], acc[x][y][r]);
      }
#pragma unroll
  for (int off = 1; off < 16; off <<= 1)
#pragma unroll
    for (int x = 0; x < 2; ++x)
#pragma unroll
      for (int r = 0; r < 4; ++r) mt[x][r] = fmaxf(mt[x][r], __shfl_xor(mt[x][r], off));
  if (l16 == 0) {
#pragma unroll
    for (int x = 0; x < 2; ++x)
#pragma unroll
      for (int r = 0; r < 4; ++r)
        mred[wj][wq * 32 + x * 16 + quad * 4 + r] = mt[x][r];
  }
  __syncthreads();
  float nrow[2][4], mu[2][4], lt[2][4];
#pragma unroll
  for (int x = 0; x < 2; ++x)
#pragma unroll
    for (int r = 0; r < 4; ++r) {
      const int rr = wq * 32 + x * 16 + quad * 4 + r;
      const float m = fmaxf(mred[0][rr], mred[1][rr]);
      const float n = ceilf(m * 1.44269504f);       // ln2 grid
      nrow[x][r] = n;
      mu[x][r] = n * 0.69314718056f;
      lt[x][r] = 0.f;
    }
  const size_t pbase = ((size_t)(b * 16 + jb)) * NQ_ * 128;
#pragma unroll
  for (int x = 0; x < 2; ++x)
#pragma unroll
    for (int y = 0; y < 4; ++y) {
      const int jloc = wj * 64 + y * 16 + l16;      // 0..127 within tile
#pragma unroll
      for (int r = 0; r < 4; ++r) {
        const int i = i0 + wq * 32 + x * 16 + quad * 4 + r;
        float p = __expf(acc[x][y][r] - mu[x][r]);
        p = fmaxf(p, 8.673617e-19f);                // clamp >= 2^-60 (no bf16 zeros)
        lt[x][r] += p;
        Pb[pbase + (size_t)i * 128 + jloc] = f2bf(p);
      }
    }
#pragma unroll
  for (int off = 1; off < 16; off <<= 1)
#pragma unroll
    for (int x = 0; x < 2; ++x)
#pragma unroll
      for (int r = 0; r < 4; ++r) lt[x][r] += __shfl_xor(lt[x][r], off);
  if (l16 == 0) {
#pragma unroll
    for (int x = 0; x < 2; ++x)
#pragma unroll
      for (int r = 0; r < 4; ++r)
        lred[wj][wq * 32 + x * 16 + quad * 4 + r] = lt[x][r];
  }
  __syncthreads();
  if (wj == 0 && l16 == 0) {
#pragma unroll
    for (int x = 0; x < 2; ++x)
#pragma unroll
      for (int r = 0; r < 4; ++r) {
        const int rr = wq * 32 + x * 16 + quad * 4 + r;
        stat[(size_t)jb * (B_ * NQ_) + (size_t)b * NQ_ + i0 + rr] =
            make_float2(nrow[x][r], lred[0][rr] + lred[1][rr]);
      }
  }
}

// ---------------------------------------------------------------------------
// per-row global stats from 16 jblock stats: srow = (n_max, 1/l)
// ---------------------------------------------------------------------------
__global__ __launch_bounds__(256) void rowfin_kernel(const float2* __restrict__ stat,
                                                     float2* __restrict__ srow) {
  const int i = blockIdx.x * 256 + threadIdx.x;   // 0..16383
  float2 st[16];
  float m = -3e38f;
#pragma unroll
  for (int jb = 0; jb < 16; ++jb) {
    st[jb] = stat[(size_t)jb * (B_ * NQ_) + i];
    m = fmaxf(m, st[jb].x);
  }
  float l = 0.f;
#pragma unroll
  for (int jb = 0; jb < 16; ++jb) l += st[jb].y * exp2f(st[jb].x - m);
  srow[i] = make_float2(m, 1.0f / l);
}

// ---------------------------------------------------------------------------
// out[m,d] = (1/l) * sum_{all j} P[m,j]*2^(n_jb-n_max) * V[j,d]
// ATOMIC-FREE (verified r6): each block owns 64 rows x ALL 2048 j -> plain
// stores. 256 blocks (1/CU), 512 threads, 64-wide j-steps, triple-buffered
// depth-2 gl16 pipeline (vmcnt(10)), XCD-remap for V L2 residency.
// ---------------------------------------------------------------------------
__global__ __launch_bounds__(512, 1) void pv_p(const unsigned short* __restrict__ Pb,
                                               const float2* __restrict__ stat,
                                               const float2* __restrict__ srow,
                                               const unsigned short* __restrict__ Vt,
                                               float* __restrict__ out) {
  __shared__ __align__(16) unsigned short Ps[3][64][64];
  __shared__ __align__(16) unsigned short Vs[3][256][64];
  const int t = threadIdx.x;
  const int lb = (blockIdx.x & 7) * 32 + (blockIdx.x >> 3);
  const int mb = lb * 64;                    // flattened row base (b*NQ + i)
  const int b  = lb >> 5;                    // batch (32 blocks per batch)
  const int i0 = mb & (NQ_ - 1);             // row within batch
  const int w = t >> 6, lane = t & 63, quad = lane >> 4, l16 = lane & 15;
  const int wm = w & 1, wd = w >> 1;         // wave: row-half (32), d-quarter (64)
  const int prow = t >> 3, pslot = t & 7;    // staging: row, 16B slot

  unsigned int es2[16][2];
  {
    float nmax[2];
#pragma unroll
    for (int x = 0; x < 2; ++x)
      nmax[x] = srow[mb + wm * 32 + x * 16 + l16].x;
#pragma unroll
    for (int jb = 0; jb < 16; ++jb)
#pragma unroll
      for (int x = 0; x < 2; ++x) {
        const int arow = mb + wm * 32 + x * 16 + l16;
        int e = (int)(nmax[x] - stat[(size_t)jb * (B_ * NQ_) + arow].x);
        e = e < 0 ? 0 : (e > 60 ? 60 : e);
        es2[jb][x] = (unsigned int)(e << 7) * 0x00010001u;
      }
  }

  f32x4_t acc[2][4];
#pragma unroll
  for (int x = 0; x < 2; ++x)
#pragma unroll
    for (int y = 0; y < 4; ++y) acc[x][y] = (f32x4_t)0.f;

  const size_t vbase = (size_t)b * D_ * (size_t)NK_;

  auto STAGE = [&](int nb, int s) {
    const int jj = s * 64;
    const int jb = jj >> 7, off = jj & 127;
    {  // P: 1 gl16/thread
      const int sg = pslot ^ (prow & 7);
      gl16(Pb + ((size_t)(b * 16 + jb)) * NQ_ * 128 +
               (size_t)(i0 + prow) * 128 + off + sg * 8,
           &Ps[nb][w * 8][0]);
    }
#pragma unroll
    for (int k = 0; k < 4; ++k) {  // V: 4 gl16/thread
      const int vrow = k * 64 + prow;
      const int sg = pslot ^ (vrow & 7);
      gl16(Vt + vbase + (size_t)vrow * NK_ + jj + sg * 8,
           &Vs[nb][k * 64 + w * 8][0]);
    }
  };

  asm volatile("s_waitcnt vmcnt(0)" ::: "memory");  // drain stat/srow loads
  STAGE(0, 0);
  STAGE(1, 1);

#pragma unroll
  for (int s = 0; s < 32; ++s) {
    const int cb = s % 3;
    if (s < 30) {
      STAGE((s + 2) % 3, s + 2);                        // depth-2 prefetch
      asm volatile("s_waitcnt vmcnt(10)" ::: "memory"); // step s ready
    } else if (s == 30) {
      asm volatile("s_waitcnt vmcnt(5)" ::: "memory");
    } else {
      asm volatile("s_waitcnt vmcnt(0)" ::: "memory");
    }
    __builtin_amdgcn_s_barrier();
    asm volatile("" ::: "memory");

    const unsigned int e0 = es2[s >> 1][0], e1 = es2[s >> 1][1];
#pragma unroll
    for (int ks = 0; ks < 2; ++ks) {
      bf16x8_t a[2], bv[4];
#pragma unroll
      for (int x = 0; x < 2; ++x) {
        const int row = wm * 32 + x * 16 + l16;
        const int sk = (ks * 4 + quad) ^ (row & 7);
        uint4 u = *(const uint4*)&Ps[cb][row][sk * 8];
        const unsigned int e = (x == 0) ? e0 : e1;
        u.x -= e; u.y -= e; u.z -= e; u.w -= e;
        a[x] = *(const bf16x8_t*)&u;                 // P * 2^(n_jb - n_max)
      }
#pragma unroll
      for (int y = 0; y < 4; ++y) {
        const int row = wd * 64 + y * 16 + l16;
        const int sk = (ks * 4 + quad) ^ (row & 7);
        bv[y] = *(const bf16x8_t*)&Vs[cb][row][sk * 8];
      }
#pragma unroll
      for (int x = 0; x < 2; ++x)
#pragma unroll
        for (int y = 0; y < 4; ++y)
          acc[x][y] = __builtin_amdgcn_mfma_f32_16x16x32_bf16(a[x], bv[y], acc[x][y], 0, 0, 0);
    }

    asm volatile("" ::: "memory");
    __builtin_amdgcn_s_barrier();
    asm volatile("" ::: "memory");
  }

#pragma unroll
  for (int x = 0; x < 2; ++x) {
    float sy[4];
#pragma unroll
    for (int r = 0; r < 4; ++r)
      sy[r] = srow[mb + wm * 32 + x * 16 + quad * 4 + r].y;
#pragma unroll
    for (int y = 0; y < 4; ++y) {
      const int d = wd * 64 + y * 16 + l16;
#pragma unroll
      for (int r = 0; r < 4; ++r) {
        const int m = mb + wm * 32 + x * 16 + quad * 4 + r;
        out[(size_t)m * D_ + d] = acc[x][y][r] * sy[r];
      }
    }
  }
}

extern "C" void kernel_launch(void* const* d_in, const int* in_sizes, int n_in,
                              void* d_out, int out_size, void* d_ws, size_t ws_size,
                              hipStream_t stream) {
  const float* query = (const float*)d_in[0];
  const float* key   = (const float*)d_in[1];
  const float* Wq    = (const float*)d_in[2];
  const float* bq    = (const float*)d_in[3];
  const float* Wk    = (const float*)d_in[4];
  const float* bk    = (const float*)d_in[5];
  float* out = (float*)d_out;

  char* ws = (char*)d_ws;
  const size_t MB = (size_t)1 << 20;
  // persistent:
  unsigned short* qh = (unsigned short*)(ws);             // 8 MB
  unsigned short* ql = (unsigned short*)(ws + 8 * MB);
  unsigned short* kh = (unsigned short*)(ws + 16 * MB);
  unsigned short* kl = (unsigned short*)(ws + 24 * MB);
  unsigned short* Vt = (unsigned short*)(ws + 32 * MB);
  unsigned short* Pb = (unsigned short*)(ws + 40 * MB);   // 64 MB (tiled [b*16+jb][2048][128])
  float2* stat = (float2*)(ws + 108 * MB);                // 2 MB
  float2* srow = (float2*)(ws + 110 * MB);                // 128 KB
  // transients (all dead before scores_p writes Pb):
  unsigned short* Ch   = (unsigned short*)(ws + 40 * MB);   // 2.43 MB (1152x1056)
  unsigned short* Cl   = (unsigned short*)(ws + 43 * MB);   // 2.43 MB
  unsigned short* Qtfh = (unsigned short*)(ws + 46 * MB);   // 4.33 MB (8x256x1056)
  unsigned short* Qtfl = (unsigned short*)(ws + 51 * MB);   // 4.33 MB
  float*          qr   = (float*)(ws + 56 * MB);            // 3 x 9.44 MB partials (56,66,76)
  unsigned short* qrh  = (unsigned short*)(ws + 40 * MB);   // 8 MB (overlays dead C'/Qtf)
  unsigned short* qrl  = (unsigned short*)(ws + 48 * MB);   // 8 MB (ends 56, before qr partials)
  unsigned short* keyh = (unsigned short*)(ws + 92 * MB);   // 8 MB
  unsigned short* keyl = (unsigned short*)(ws + 100 * MB);  // 8 MB
  unsigned short* Wqh  = (unsigned short*)(ws + 111 * MB);  // 128 KB
  unsigned short* Wql  = (unsigned short*)(ws + 111 * MB + 256 * 1024);
  unsigned short* Wkh  = (unsigned short*)(ws + 111 * MB + 512 * 1024);
  unsigned short* Wkl  = (unsigned short*)(ws + 111 * MB + 768 * 1024);

  dim3 blk(256);

  // fused: key split + Vt transpose (one 16MB read, one launch)
  key_split_vt<<<dim3(NK_ / 32, B_), blk, 0, stream>>>(key, keyh, keyl, Vt);
  split_kernel<<<D_ * D_ / 256, blk, 0, stream>>>(Wq, Wqh, Wql, D_ * D_);
  split_kernel<<<D_ * D_ / 256, blk, 0, stream>>>(Wk, Wkh, Wkl, D_ * D_);
  cos_split_kernel<<<1152 * KF_ / 256, blk, 0, stream>>>(Ch, Cl);
  qtf_split_kernel<<<dim3(KF_ / 32, D_ / 32, B_), blk, 0, stream>>>(query, Qtfh, Qtfl);
  // folded DFT: K=1056, 3-way K-split into private partial buffers
  dft_mfma<<<dim3(9, 2, B_ * 3), blk, 0, stream>>>(Ch, Cl, Qtfh, Qtfl, qr);
  qr_finalize_kernel<<<dim3(2048, B_), blk, 0, stream>>>(qr, qrh, qrl);
  // projections
  proj_mfma<<<dim3(B_ * NQ_ / 128, 2), blk, 0, stream>>>(qrh, qrl, Wqh, Wql, bq, qh, ql);
  proj_mfma<<<dim3(B_ * NK_ / 128, 2), blk, 0, stream>>>(keyh, keyl, Wkh, Wkl, bk, kh, kl);
  // attention: scores (bf16 P + per-jb pow2 stats) -> per-row stats -> PV
  scores_p<<<dim3(NQ_ / 128, NK_ / 128, B_), dim3(512), 0, stream>>>(qh, ql, kh, kl, Pb, stat);
  rowfin_kernel<<<B_ * NQ_ / 256, blk, 0, stream>>>(stat, srow);
  pv_p<<<dim3(256), dim3(512), 0, stream>>>(Pb, stat, srow, Vt, out);
}

// Round 13
// 192.365 us; speedup vs baseline: 1.1264x; 1.0455x over previous
//
#include <hip/hip_runtime.h>

#define B_ 8
#define NQ_ 2048
#define NK_ 2048
#define D_ 256
#define KF_ 1056   // folded DFT K (1025 live + pad), 33 steps of 32

typedef __attribute__((ext_vector_type(8))) short bf16x8_t;
typedef __attribute__((ext_vector_type(4))) float f32x4_t;

static __device__ __forceinline__ unsigned short f2bf(float x) {
  unsigned int u = __float_as_uint(x);
  unsigned int r = (u + 0x7FFFu + ((u >> 16) & 1u)) >> 16;
  return (unsigned short)r;
}
static __device__ __forceinline__ float bf2f(unsigned short b) {
  return __uint_as_float(((unsigned int)b) << 16);
}

typedef __attribute__((address_space(1))) unsigned int gas_u32;
typedef __attribute__((address_space(3))) unsigned int las_u32;
static __device__ __forceinline__ void gl16(const void* g, void* l) {
  __builtin_amdgcn_global_load_lds((const gas_u32*)g, (las_u32*)l, 16, 0, 0);
}

// ---------------------------------------------------------------------------
// fused Wq+Wk f32 -> split bf16 (hi + lo), one launch
// ---------------------------------------------------------------------------
__global__ __launch_bounds__(256) void wsplit_kernel(const float* __restrict__ Wq,
                                                     const float* __restrict__ Wk,
                                                     unsigned short* __restrict__ Wqh,
                                                     unsigned short* __restrict__ Wql,
                                                     unsigned short* __restrict__ Wkh,
                                                     unsigned short* __restrict__ Wkl) {
  const int i = blockIdx.x * 256 + threadIdx.x;   // 0 .. 2*D*D-1
  const int n = D_ * D_;
  const float* x = (i < n) ? Wq : Wk;
  unsigned short* xh = (i < n) ? Wqh : Wkh;
  unsigned short* xl = (i < n) ? Wql : Wkl;
  const int j = (i < n) ? i : i - n;
  const float v = x[j];
  const unsigned short hb = f2bf(v);
  xh[j] = hb;
  xl[j] = f2bf(v - bf2f(hb));
}

// Fused: key f32 -> keyh/keyl (split bf16, coalesced row writes) AND
// Vt[b][d][j] = keyh (transposed via LDS). (verified r12)
__global__ __launch_bounds__(256) void key_split_vt(const float* __restrict__ key,
                                                    unsigned short* __restrict__ keyh,
                                                    unsigned short* __restrict__ keyl,
                                                    unsigned short* __restrict__ Vt) {
  __shared__ unsigned short lds[32][258];   // 129-dword row stride: conflict-free transpose
  const int t = threadIdx.x;
  const int j0 = blockIdx.x * 32;
  const int b  = blockIdx.y;
#pragma unroll
  for (int p = 0; p < 32; ++p) {
    const size_t g = ((size_t)b * NK_ + j0 + p) * D_ + t;
    const float v = key[g];
    const unsigned short hb = f2bf(v);
    keyh[g] = hb;
    keyl[g] = f2bf(v - bf2f(hb));
    lds[p][t] = hb;
  }
  __syncthreads();
#pragma unroll
  for (int p = 0; p < 32; ++p) {
    const int jj = t & 31;
    const int d  = (t >> 5) + 8 * p;
    Vt[((size_t)b * D_ + d) * NK_ + j0 + jj] = lds[jj][d];
  }
}

// C'[i][n] = cos(2*pi*(i*n mod 2048)/2048) for n<=1024, 0 for pad; split bf16
__global__ __launch_bounds__(256) void cos_split_kernel(unsigned short* __restrict__ Ch,
                                                        unsigned short* __restrict__ Cl) {
  const int idx = blockIdx.x * 256 + threadIdx.x;   // 1152*1056 total
  const int i = idx / KF_, n = idx % KF_;
  float c = 0.f;
  if (n <= 1024) {
    const int m = (i * n) & 2047;
    c = cosf((float)m * 0.0030679615757712823f);
  }
  const unsigned short hb = f2bf(c);
  Ch[idx] = hb;
  Cl[idx] = f2bf(c - bf2f(hb));
}

// Folded + transposed query: Qtf[b][d][n] = split(q[b][n][d] + q[b][2048-n][d])
// for n in 1..1023; n=0 -> q[0]; n=1024 -> q[1024]; n>=1025 -> 0.
__global__ __launch_bounds__(256) void qtf_split_kernel(const float* __restrict__ q,
                                                        unsigned short* __restrict__ Qtfh,
                                                        unsigned short* __restrict__ Qtfl) {
  __shared__ float lds[32][33];
  const int t  = threadIdx.x;
  const int n0 = blockIdx.x * 32;    // 33 tiles -> n up to 1055
  const int d0 = blockIdx.y * 32;
  const int b  = blockIdx.z;
#pragma unroll
  for (int p = 0; p < 4; ++p) {
    const int idx = t + 256 * p;
    const int dd = idx & 31, nn = idx >> 5;
    const int n = n0 + nn;
    float v = 0.f;
    if (n <= 1024) v = q[((size_t)b * NQ_ + n) * D_ + d0 + dd];
    if (n >= 1 && n <= 1023) v += q[((size_t)b * NQ_ + (2048 - n)) * D_ + d0 + dd];
    lds[nn][dd] = v;
  }
  __syncthreads();
#pragma unroll
  for (int p = 0; p < 4; ++p) {
    const int idx = t + 256 * p;
    const int nn = idx & 31, dd = idx >> 5;
    const float v = lds[nn][dd];
    const unsigned short hb = f2bf(v);
    const size_t o = ((size_t)b * D_ + d0 + dd) * KF_ + n0 + nn;
    Qtfh[o] = hb;
    Qtfl[o] = f2bf(v - bf2f(hb));
  }
}

// ---------------------------------------------------------------------------
// Folded DFT via split-bf16 3-MFMA. K = 1056, K-split=3 (352 = 11 steps of 32)
// with PRIVATE partial buffers + plain stores. (verified r8)
// ---------------------------------------------------------------------------
__global__ __launch_bounds__(256, 2) void dft_mfma(const unsigned short* __restrict__ Ch,
                                                   const unsigned short* __restrict__ Cl,
                                                   const unsigned short* __restrict__ Qtfh,
                                                   const unsigned short* __restrict__ Qtfl,
                                                   float* __restrict__ qr) {
  __shared__ __align__(16) unsigned short Ah[128][40];
  __shared__ __align__(16) unsigned short Al[128][40];
  __shared__ __align__(16) unsigned short Bh[128][40];
  __shared__ __align__(16) unsigned short Bl[128][40];
  const int t = threadIdx.x;
  const int b = blockIdx.z / 3, split = blockIdx.z % 3;
  const int i0 = blockIdx.x * 128, d0 = blockIdx.y * 128;
  const int w = t >> 6, lane = t & 63, quad = lane >> 4, l16 = lane & 15;
  const int wq = w & 1, wj = w >> 1;
  float* qrs = qr + (size_t)split * ((size_t)B_ * 1152 * D_);

  f32x4_t acc[4][4];
#pragma unroll
  for (int a = 0; a < 4; ++a)
#pragma unroll
    for (int c = 0; c < 4; ++c) acc[a][c] = (f32x4_t)0.f;

  const size_t abase = (size_t)i0 * KF_;
  const size_t bbase = ((size_t)b * D_ + d0) * KF_;

  for (int c0 = split * 352; c0 < split * 352 + 352; c0 += 32) {
#pragma unroll
    for (int it = 0; it < 2; ++it) {
      const int unit = t + 256 * it;           // 512 units = 128 rows x 4 slots
      const int row = unit >> 2, u = (unit & 3) * 8;
      const size_t go = (size_t)row * KF_ + c0 + u;
      *(uint4*)&Ah[row][u] = *(const uint4*)&Ch[abase + go];
      *(uint4*)&Al[row][u] = *(const uint4*)&Cl[abase + go];
      *(uint4*)&Bh[row][u] = *(const uint4*)&Qtfh[bbase + go];
      *(uint4*)&Bl[row][u] = *(const uint4*)&Qtfl[bbase + go];
    }
    __syncthreads();
    {
      const int dcol = quad * 8;
      bf16x8_t ah[4], al[4], bh[4], bl[4];
#pragma unroll
      for (int x = 0; x < 4; ++x) {
        ah[x] = *(const bf16x8_t*)&Ah[wq * 64 + x * 16 + l16][dcol];
        al[x] = *(const bf16x8_t*)&Al[wq * 64 + x * 16 + l16][dcol];
        bh[x] = *(const bf16x8_t*)&Bh[wj * 64 + x * 16 + l16][dcol];
        bl[x] = *(const bf16x8_t*)&Bl[wj * 64 + x * 16 + l16][dcol];
      }
#pragma unroll
      for (int at = 0; at < 4; ++at)
#pragma unroll
        for (int jt = 0; jt < 4; ++jt) {
          acc[at][jt] = __builtin_amdgcn_mfma_f32_16x16x32_bf16(ah[at], bh[jt], acc[at][jt], 0, 0, 0);
          acc[at][jt] = __builtin_amdgcn_mfma_f32_16x16x32_bf16(ah[at], bl[jt], acc[at][jt], 0, 0, 0);
          acc[at][jt] = __builtin_amdgcn_mfma_f32_16x16x32_bf16(al[at], bh[jt], acc[at][jt], 0, 0, 0);
        }
    }
    __syncthreads();
  }
#pragma unroll
  for (int at = 0; at < 4; ++at) {
#pragma unroll
    for (int jt = 0; jt < 4; ++jt) {
      const int d = d0 + wj * 64 + jt * 16 + l16;
#pragma unroll
      for (int r = 0; r < 4; ++r) {
        const int i = i0 + wq * 64 + at * 16 + quad * 4 + r;
        qrs[((size_t)b * 1152 + i) * D_ + d] = acc[at][jt][r];
      }
    }
  }
}

// qrh/qrl[b][i][d]: sum 3 partials; src = i<=1087 ? i : 2048-i
__global__ __launch_bounds__(256) void qr_finalize_kernel(const float* __restrict__ qr,
                                                          unsigned short* __restrict__ qrh,
                                                          unsigned short* __restrict__ qrl) {
  const int i = blockIdx.x, b = blockIdx.y, d = threadIdx.x;
  const int src = (i <= 1087) ? i : (2048 - i);
  const size_t S = (size_t)B_ * 1152 * D_;
  const size_t idx = ((size_t)b * 1152 + src) * D_ + d;
  const float v = qr[idx] + qr[idx + S] + qr[idx + 2 * S];
  const unsigned short hb = f2bf(v);
  const size_t o = ((size_t)b * NQ_ + i) * D_ + d;
  qrh[o] = hb;
  qrl[o] = f2bf(v - bf2f(hb));
}

// ---------------------------------------------------------------------------
// BATCHED projections: y = x @ W.T + bias for BOTH q and k in one launch
// (blockIdx.z selects operand set). 512 blocks = 2/CU (was 2x256 = 1/CU).
// Body identical to verified r3/r4 proj_mfma.
// ---------------------------------------------------------------------------
__global__ __launch_bounds__(256, 2) void proj_mfma2(
    const unsigned short* __restrict__ xh0, const unsigned short* __restrict__ xl0,
    const unsigned short* __restrict__ Wh0, const unsigned short* __restrict__ Wl0,
    const float* __restrict__ b0,
    unsigned short* __restrict__ yh0, unsigned short* __restrict__ yl0,
    const unsigned short* __restrict__ xh1, const unsigned short* __restrict__ xl1,
    const unsigned short* __restrict__ Wh1, const unsigned short* __restrict__ Wl1,
    const float* __restrict__ b1,
    unsigned short* __restrict__ yh1, unsigned short* __restrict__ yl1) {
  const int z = blockIdx.z;
  const unsigned short* xh = z ? xh1 : xh0;
  const unsigned short* xl = z ? xl1 : xl0;
  const unsigned short* Wh = z ? Wh1 : Wh0;
  const unsigned short* Wl = z ? Wl1 : Wl0;
  const float* bias = z ? b1 : b0;
  unsigned short* yh = z ? yh1 : yh0;
  unsigned short* yl = z ? yl1 : yl0;

  __shared__ __align__(16) unsigned short Xh[128][72];
  __shared__ __align__(16) unsigned short Xl[128][72];
  __shared__ __align__(16) unsigned short Bh[128][72];
  __shared__ __align__(16) unsigned short Bl[128][72];
  const int t = threadIdx.x;
  const int m0 = blockIdx.x * 128, o0 = blockIdx.y * 128;
  const int w = t >> 6, lane = t & 63, quad = lane >> 4, l16 = lane & 15;
  const int wq = w & 1, wj = w >> 1;

  f32x4_t acc[4][4];
#pragma unroll
  for (int a = 0; a < 4; ++a)
#pragma unroll
    for (int c = 0; c < 4; ++c) acc[a][c] = (f32x4_t)0.f;

  const size_t xbase = (size_t)m0 * D_;
  const size_t wbase = (size_t)o0 * D_;

  for (int c0 = 0; c0 < D_; c0 += 64) {
#pragma unroll
    for (int it = 0; it < 4; ++it) {
      const int unit = t + 256 * it;
      const int row = unit >> 3, u = (unit & 7) * 8;
      const size_t go = (size_t)row * D_ + c0 + u;
      *(uint4*)&Xh[row][u] = *(const uint4*)&xh[xbase + go];
      *(uint4*)&Xl[row][u] = *(const uint4*)&xl[xbase + go];
      *(uint4*)&Bh[row][u] = *(const uint4*)&Wh[wbase + go];
      *(uint4*)&Bl[row][u] = *(const uint4*)&Wl[wbase + go];
    }
    __syncthreads();
#pragma unroll
    for (int ks = 0; ks < 2; ++ks) {
      const int dcol = ks * 32 + quad * 8;
      bf16x8_t ah[4], al[4], bh[4], bl[4];
#pragma unroll
      for (int x = 0; x < 4; ++x) {
        ah[x] = *(const bf16x8_t*)&Xh[wq * 64 + x * 16 + l16][dcol];
        al[x] = *(const bf16x8_t*)&Xl[wq * 64 + x * 16 + l16][dcol];
        bh[x] = *(const bf16x8_t*)&Bh[wj * 64 + x * 16 + l16][dcol];
        bl[x] = *(const bf16x8_t*)&Bl[wj * 64 + x * 16 + l16][dcol];
      }
#pragma unroll
      for (int at = 0; at < 4; ++at)
#pragma unroll
        for (int jt = 0; jt < 4; ++jt) {
          acc[at][jt] = __builtin_amdgcn_mfma_f32_16x16x32_bf16(ah[at], bh[jt], acc[at][jt], 0, 0, 0);
          acc[at][jt] = __builtin_amdgcn_mfma_f32_16x16x32_bf16(ah[at], bl[jt], acc[at][jt], 0, 0, 0);
          acc[at][jt] = __builtin_amdgcn_mfma_f32_16x16x32_bf16(al[at], bh[jt], acc[at][jt], 0, 0, 0);
        }
    }
    __syncthreads();
  }
#pragma unroll
  for (int at = 0; at < 4; ++at) {
#pragma unroll
    for (int jt = 0; jt < 4; ++jt) {
      const int o = o0 + wj * 64 + jt * 16 + l16;
      const float bv = bias[o];
#pragma unroll
      for (int r = 0; r < 4; ++r) {
        const int m = m0 + wq * 64 + at * 16 + quad * 4 + r;
        const float v = acc[at][jt][r] + bv;
        const unsigned short hb = f2bf(v);
        yh[(size_t)m * D_ + o] = hb;
        yl[(size_t)m * D_ + o] = f2bf(v - bf2f(hb));
      }
    }
  }
}

// ---------------------------------------------------------------------------
// scores + per-jblock softmax stats. 8-wave, BK=64 SINGLE-BUFFER m97-style
// (verified r9): step = { vmcnt(0) -> barrier -> ds_read + MFMA -> barrier ->
// stage next (8 gl16/thread) }. 66KB LDS keeps 2 blocks/CU (16 waves).
// XOR swizzle: slot ^ (row&7). Pb TILED: Pb[(b*16+jb)][i][128]. ln2 offsets.
// ---------------------------------------------------------------------------
__global__ __launch_bounds__(512, 4) void scores_p(const unsigned short* __restrict__ qh,
                                                   const unsigned short* __restrict__ ql,
                                                   const unsigned short* __restrict__ kh,
                                                   const unsigned short* __restrict__ kl,
                                                   unsigned short* __restrict__ Pb,
                                                   float2* __restrict__ stat) {
  __shared__ __align__(16) unsigned short Qh[128][64];
  __shared__ __align__(16) unsigned short Ql[128][64];
  __shared__ __align__(16) unsigned short Kh[128][64];
  __shared__ __align__(16) unsigned short Kl[128][64];
  __shared__ float mred[2][128];
  __shared__ float lred[2][128];
  const int t = threadIdx.x;
  const int b = blockIdx.z;
  const int i0 = blockIdx.x * 128, j0 = blockIdx.y * 128;
  const int jb = blockIdx.y;   // 0..15
  const int w = t >> 6, lane = t & 63, quad = lane >> 4, l16 = lane & 15;
  const int wq = w & 3, wj = w >> 2;         // 4 row-groups x 2 col-groups
  const int sr0 = t >> 3, ssl = t & 7;       // staging: row 0..63, 16B slot 0..7

  f32x4_t acc[2][4];
#pragma unroll
  for (int x = 0; x < 2; ++x)
#pragma unroll
    for (int y = 0; y < 4; ++y) acc[x][y] = (f32x4_t)0.f;

  const size_t qbase = ((size_t)b * NQ_ + i0) * D_;
  const size_t kbase = ((size_t)b * NK_ + j0) * D_;

  auto STAGE = [&](int c0) {
#pragma unroll
    for (int half = 0; half < 2; ++half) {
      const int row = half * 64 + sr0;
      const int sg = (ssl ^ (row & 7)) * 8;
      const size_t ro = (size_t)row * D_ + c0 + sg;
      gl16(qh + qbase + ro, &Qh[half * 64 + w * 8][0]);
      gl16(ql + qbase + ro, &Ql[half * 64 + w * 8][0]);
      gl16(kh + kbase + ro, &Kh[half * 64 + w * 8][0]);
      gl16(kl + kbase + ro, &Kl[half * 64 + w * 8][0]);
    }
  };

  STAGE(0);   // prologue

#pragma unroll
  for (int s = 0; s < 4; ++s) {
    asm volatile("s_waitcnt vmcnt(0)" ::: "memory");   // tile s staged
    __builtin_amdgcn_s_barrier();
    asm volatile("" ::: "memory");

#pragma unroll
    for (int ks = 0; ks < 2; ++ks) {
      bf16x8_t ah[2], al[2], bh[4], bl[4];
#pragma unroll
      for (int x = 0; x < 2; ++x) {
        const int ar = wq * 32 + x * 16 + l16;
        const int asl = ((ks * 4 + quad) ^ (ar & 7)) * 8;
        ah[x] = *(const bf16x8_t*)&Qh[ar][asl];
        al[x] = *(const bf16x8_t*)&Ql[ar][asl];
      }
#pragma unroll
      for (int y = 0; y < 4; ++y) {
        const int br = wj * 64 + y * 16 + l16;
        const int bsl = ((ks * 4 + quad) ^ (br & 7)) * 8;
        bh[y] = *(const bf16x8_t*)&Kh[br][bsl];
        bl[y] = *(const bf16x8_t*)&Kl[br][bsl];
      }
#pragma unroll
      for (int x = 0; x < 2; ++x)
#pragma unroll
        for (int y = 0; y < 4; ++y) {
          acc[x][y] = __builtin_amdgcn_mfma_f32_16x16x32_bf16(ah[x], bh[y], acc[x][y], 0, 0, 0);
          acc[x][y] = __builtin_amdgcn_mfma_f32_16x16x32_bf16(ah[x], bl[y], acc[x][y], 0, 0, 0);
          acc[x][y] = __builtin_amdgcn_mfma_f32_16x16x32_bf16(al[x], bh[y], acc[x][y], 0, 0, 0);
        }
    }

    asm volatile("" ::: "memory");
    __builtin_amdgcn_s_barrier();
    asm volatile("" ::: "memory");
    if (s < 3) STAGE((s + 1) * 64);                    // overwrite buffer
  }

  // --- epilogue: per-row (over this block's 128 j) max, exp, sum, bf16 store
  const float scale = 0.0625f;
  float mt[2][4];
#pragma unroll
  for (int x = 0; x < 2; ++x)
#pragma unroll
    for (int r = 0; r < 4; ++r) mt[x][r] = -3e38f;
#pragma unroll
  for (int x = 0; x < 2; ++x)
#pragma unroll
    for (int y = 0; y < 4; ++y)
#pragma unroll
      for (int r = 0; r < 4; ++r) {
        acc[x][y][r] *= scale;
        mt[x][r] = fmaxf(mt[x][r], acc[x][y][r]);
      }
#pragma unroll
  for (int off = 1; off < 16; off <<= 1)
#pragma unroll
    for (int x = 0; x < 2; ++x)
#pragma unroll
      for (int r = 0; r < 4; ++r) mt[x][r] = fmaxf(mt[x][r], __shfl_xor(mt[x][r], off));
  if (l16 == 0) {
#pragma unroll
    for (int x = 0; x < 2; ++x)
#pragma unroll
      for (int r = 0; r < 4; ++r)
        mred[wj][wq * 32 + x * 16 + quad * 4 + r] = mt[x][r];
  }
  __syncthreads();
  float nrow[2][4], mu[2][4], lt[2][4];
#pragma unroll
  for (int x = 0; x < 2; ++x)
#pragma unroll
    for (int r = 0; r < 4; ++r) {
      const int rr = wq * 32 + x * 16 + quad * 4 + r;
      const float m = fmaxf(mred[0][rr], mred[1][rr]);
      const float n = ceilf(m * 1.44269504f);       // ln2 grid
      nrow[x][r] = n;
      mu[x][r] = n * 0.69314718056f;
      lt[x][r] = 0.f;
    }
  const size_t pbase = ((size_t)(b * 16 + jb)) * NQ_ * 128;
#pragma unroll
  for (int x = 0; x < 2; ++x)
#pragma unroll
    for (int y = 0; y < 4; ++y) {
      const int jloc = wj * 64 + y * 16 + l16;      // 0..127 within tile
#pragma unroll
      for (int r = 0; r < 4; ++r) {
        const int i = i0 + wq * 32 + x * 16 + quad * 4 + r;
        float p = __expf(acc[x][y][r] - mu[x][r]);
        p = fmaxf(p, 8.673617e-19f);                // clamp >= 2^-60 (no bf16 zeros)
        lt[x][r] += p;
        Pb[pbase + (size_t)i * 128 + jloc] = f2bf(p);
      }
    }
#pragma unroll
  for (int off = 1; off < 16; off <<= 1)
#pragma unroll
    for (int x = 0; x < 2; ++x)
#pragma unroll
      for (int r = 0; r < 4; ++r) lt[x][r] += __shfl_xor(lt[x][r], off);
  if (l16 == 0) {
#pragma unroll
    for (int x = 0; x < 2; ++x)
#pragma unroll
      for (int r = 0; r < 4; ++r)
        lred[wj][wq * 32 + x * 16 + quad * 4 + r] = lt[x][r];
  }
  __syncthreads();
  if (wj == 0 && l16 == 0) {
#pragma unroll
    for (int x = 0; x < 2; ++x)
#pragma unroll
      for (int r = 0; r < 4; ++r) {
        const int rr = wq * 32 + x * 16 + quad * 4 + r;
        stat[(size_t)jb * (B_ * NQ_) + (size_t)b * NQ_ + i0 + rr] =
            make_float2(nrow[x][r], lred[0][rr] + lred[1][rr]);
      }
  }
}

// ---------------------------------------------------------------------------
// per-row global stats from 16 jblock stats: srow = (n_max, 1/l)
// ---------------------------------------------------------------------------
__global__ __launch_bounds__(256) void rowfin_kernel(const float2* __restrict__ stat,
                                                     float2* __restrict__ srow) {
  const int i = blockIdx.x * 256 + threadIdx.x;   // 0..16383
  float2 st[16];
  float m = -3e38f;
#pragma unroll
  for (int jb = 0; jb < 16; ++jb) {
    st[jb] = stat[(size_t)jb * (B_ * NQ_) + i];
    m = fmaxf(m, st[jb].x);
  }
  float l = 0.f;
#pragma unroll
  for (int jb = 0; jb < 16; ++jb) l += st[jb].y * exp2f(st[jb].x - m);
  srow[i] = make_float2(m, 1.0f / l);
}

// ---------------------------------------------------------------------------
// out[m,d] = (1/l) * sum_{all j} P[m,j]*2^(n_jb-n_max) * V[j,d]
// ATOMIC-FREE (verified r6): each block owns 64 rows x ALL 2048 j -> plain
// stores. 256 blocks (1/CU), 512 threads, 64-wide j-steps, triple-buffered
// depth-2 gl16 pipeline (vmcnt(10)), XCD-remap for V L2 residency.
// ---------------------------------------------------------------------------
__global__ __launch_bounds__(512, 1) void pv_p(const unsigned short* __restrict__ Pb,
                                               const float2* __restrict__ stat,
                                               const float2* __restrict__ srow,
                                               const unsigned short* __restrict__ Vt,
                                               float* __restrict__ out) {
  __shared__ __align__(16) unsigned short Ps[3][64][64];
  __shared__ __align__(16) unsigned short Vs[3][256][64];
  const int t = threadIdx.x;
  const int lb = (blockIdx.x & 7) * 32 + (blockIdx.x >> 3);
  const int mb = lb * 64;                    // flattened row base (b*NQ + i)
  const int b  = lb >> 5;                    // batch (32 blocks per batch)
  const int i0 = mb & (NQ_ - 1);             // row within batch
  const int w = t >> 6, lane = t & 63, quad = lane >> 4, l16 = lane & 15;
  const int wm = w & 1, wd = w >> 1;         // wave: row-half (32), d-quarter (64)
  const int prow = t >> 3, pslot = t & 7;    // staging: row, 16B slot

  unsigned int es2[16][2];
  {
    float nmax[2];
#pragma unroll
    for (int x = 0; x < 2; ++x)
      nmax[x] = srow[mb + wm * 32 + x * 16 + l16].x;
#pragma unroll
    for (int jb = 0; jb < 16; ++jb)
#pragma unroll
      for (int x = 0; x < 2; ++x) {
        const int arow = mb + wm * 32 + x * 16 + l16;
        int e = (int)(nmax[x] - stat[(size_t)jb * (B_ * NQ_) + arow].x);
        e = e < 0 ? 0 : (e > 60 ? 60 : e);
        es2[jb][x] = (unsigned int)(e << 7) * 0x00010001u;
      }
  }

  f32x4_t acc[2][4];
#pragma unroll
  for (int x = 0; x < 2; ++x)
#pragma unroll
    for (int y = 0; y < 4; ++y) acc[x][y] = (f32x4_t)0.f;

  const size_t vbase = (size_t)b * D_ * (size_t)NK_;

  auto STAGE = [&](int nb, int s) {
    const int jj = s * 64;
    const int jb = jj >> 7, off = jj & 127;
    {  // P: 1 gl16/thread
      const int sg = pslot ^ (prow & 7);
      gl16(Pb + ((size_t)(b * 16 + jb)) * NQ_ * 128 +
               (size_t)(i0 + prow) * 128 + off + sg * 8,
           &Ps[nb][w * 8][0]);
    }
#pragma unroll
    for (int k = 0; k < 4; ++k) {  // V: 4 gl16/thread
      const int vrow = k * 64 + prow;
      const int sg = pslot ^ (vrow & 7);
      gl16(Vt + vbase + (size_t)vrow * NK_ + jj + sg * 8,
           &Vs[nb][k * 64 + w * 8][0]);
    }
  };

  asm volatile("s_waitcnt vmcnt(0)" ::: "memory");  // drain stat/srow loads
  STAGE(0, 0);
  STAGE(1, 1);

#pragma unroll
  for (int s = 0; s < 32; ++s) {
    const int cb = s % 3;
    if (s < 30) {
      STAGE((s + 2) % 3, s + 2);                        // depth-2 prefetch
      asm volatile("s_waitcnt vmcnt(10)" ::: "memory"); // step s ready
    } else if (s == 30) {
      asm volatile("s_waitcnt vmcnt(5)" ::: "memory");
    } else {
      asm volatile("s_waitcnt vmcnt(0)" ::: "memory");
    }
    __builtin_amdgcn_s_barrier();
    asm volatile("" ::: "memory");

    const unsigned int e0 = es2[s >> 1][0], e1 = es2[s >> 1][1];
#pragma unroll
    for (int ks = 0; ks < 2; ++ks) {
      bf16x8_t a[2], bv[4];
#pragma unroll
      for (int x = 0; x < 2; ++x) {
        const int row = wm * 32 + x * 16 + l16;
        const int sk = (ks * 4 + quad) ^ (row & 7);
        uint4 u = *(const uint4*)&Ps[cb][row][sk * 8];
        const unsigned int e = (x == 0) ? e0 : e1;
        u.x -= e; u.y -= e; u.z -= e; u.w -= e;
        a[x] = *(const bf16x8_t*)&u;                 // P * 2^(n_jb - n_max)
      }
#pragma unroll
      for (int y = 0; y < 4; ++y) {
        const int row = wd * 64 + y * 16 + l16;
        const int sk = (ks * 4 + quad) ^ (row & 7);
        bv[y] = *(const bf16x8_t*)&Vs[cb][row][sk * 8];
      }
#pragma unroll
      for (int x = 0; x < 2; ++x)
#pragma unroll
        for (int y = 0; y < 4; ++y)
          acc[x][y] = __builtin_amdgcn_mfma_f32_16x16x32_bf16(a[x], bv[y], acc[x][y], 0, 0, 0);
    }

    asm volatile("" ::: "memory");
    __builtin_amdgcn_s_barrier();
    asm volatile("" ::: "memory");
  }

#pragma unroll
  for (int x = 0; x < 2; ++x) {
    float sy[4];
#pragma unroll
    for (int r = 0; r < 4; ++r)
      sy[r] = srow[mb + wm * 32 + x * 16 + quad * 4 + r].y;
#pragma unroll
    for (int y = 0; y < 4; ++y) {
      const int d = wd * 64 + y * 16 + l16;
#pragma unroll
      for (int r = 0; r < 4; ++r) {
        const int m = mb + wm * 32 + x * 16 + quad * 4 + r;
        out[(size_t)m * D_ + d] = acc[x][y][r] * sy[r];
      }
    }
  }
}

extern "C" void kernel_launch(void* const* d_in, const int* in_sizes, int n_in,
                              void* d_out, int out_size, void* d_ws, size_t ws_size,
                              hipStream_t stream) {
  const float* query = (const float*)d_in[0];
  const float* key   = (const float*)d_in[1];
  const float* Wq    = (const float*)d_in[2];
  const float* bq    = (const float*)d_in[3];
  const float* Wk    = (const float*)d_in[4];
  const float* bk    = (const float*)d_in[5];
  float* out = (float*)d_out;

  char* ws = (char*)d_ws;
  const size_t MB = (size_t)1 << 20;
  // persistent:
  unsigned short* qh = (unsigned short*)(ws);             // 8 MB
  unsigned short* ql = (unsigned short*)(ws + 8 * MB);
  unsigned short* kh = (unsigned short*)(ws + 16 * MB);
  unsigned short* kl = (unsigned short*)(ws + 24 * MB);
  unsigned short* Vt = (unsigned short*)(ws + 32 * MB);
  unsigned short* Pb = (unsigned short*)(ws + 40 * MB);   // 64 MB (tiled [b*16+jb][2048][128])
  float2* stat = (float2*)(ws + 108 * MB);                // 2 MB
  float2* srow = (float2*)(ws + 110 * MB);                // 128 KB
  // transients (all dead before scores_p writes Pb):
  unsigned short* Ch   = (unsigned short*)(ws + 40 * MB);   // 2.43 MB (1152x1056)
  unsigned short* Cl   = (unsigned short*)(ws + 43 * MB);   // 2.43 MB
  unsigned short* Qtfh = (unsigned short*)(ws + 46 * MB);   // 4.33 MB (8x256x1056)
  unsigned short* Qtfl = (unsigned short*)(ws + 51 * MB);   // 4.33 MB
  float*          qr   = (float*)(ws + 56 * MB);            // 3 x 9.44 MB partials (56,66,76)
  unsigned short* qrh  = (unsigned short*)(ws + 40 * MB);   // 8 MB (overlays dead C'/Qtf)
  unsigned short* qrl  = (unsigned short*)(ws + 48 * MB);   // 8 MB (ends 56, before qr partials)
  unsigned short* keyh = (unsigned short*)(ws + 92 * MB);   // 8 MB
  unsigned short* keyl = (unsigned short*)(ws + 100 * MB);  // 8 MB
  unsigned short* Wqh  = (unsigned short*)(ws + 111 * MB);  // 128 KB
  unsigned short* Wql  = (unsigned short*)(ws + 111 * MB + 256 * 1024);
  unsigned short* Wkh  = (unsigned short*)(ws + 111 * MB + 512 * 1024);
  unsigned short* Wkl  = (unsigned short*)(ws + 111 * MB + 768 * 1024);

  dim3 blk(256);

  // fused: key split + Vt transpose (one 16MB read, one launch)
  key_split_vt<<<dim3(NK_ / 32, B_), blk, 0, stream>>>(key, keyh, keyl, Vt);
  wsplit_kernel<<<2 * D_ * D_ / 256, blk, 0, stream>>>(Wq, Wk, Wqh, Wql, Wkh, Wkl);
  cos_split_kernel<<<1152 * KF_ / 256, blk, 0, stream>>>(Ch, Cl);
  qtf_split_kernel<<<dim3(KF_ / 32, D_ / 32, B_), blk, 0, stream>>>(query, Qtfh, Qtfl);
  // folded DFT: K=1056, 3-way K-split into private partial buffers
  dft_mfma<<<dim3(9, 2, B_ * 3), blk, 0, stream>>>(Ch, Cl, Qtfh, Qtfl, qr);
  qr_finalize_kernel<<<dim3(2048, B_), blk, 0, stream>>>(qr, qrh, qrl);
  // batched projections (q and k in one launch, 2 blocks/CU)
  proj_mfma2<<<dim3(B_ * NQ_ / 128, 2, 2), blk, 0, stream>>>(
      qrh, qrl, Wqh, Wql, bq, qh, ql,
      keyh, keyl, Wkh, Wkl, bk, kh, kl);
  // attention: scores (bf16 P + per-jb pow2 stats) -> per-row stats -> PV
  scores_p<<<dim3(NQ_ / 128, NK_ / 128, B_), dim3(512), 0, stream>>>(qh, ql, kh, kl, Pb, stat);
  rowfin_kernel<<<B_ * NQ_ / 256, blk, 0, stream>>>(stat, srow);
  pv_p<<<dim3(256), dim3(512), 0, stream>>>(Pb, stat, srow, Vt, out);
}

// Round 14
// 184.309 us; speedup vs baseline: 1.1756x; 1.0437x over previous
//
#include <hip/hip_runtime.h>

#define B_ 8
#define NQ_ 2048
#define NK_ 2048
#define D_ 256
#define KF_ 1056   // folded DFT K (1025 live + pad), 33 steps of 32

typedef __attribute__((ext_vector_type(8))) short bf16x8_t;
typedef __attribute__((ext_vector_type(4))) float f32x4_t;

static __device__ __forceinline__ unsigned short f2bf(float x) {
  unsigned int u = __float_as_uint(x);
  unsigned int r = (u + 0x7FFFu + ((u >> 16) & 1u)) >> 16;
  return (unsigned short)r;
}
static __device__ __forceinline__ float bf2f(unsigned short b) {
  return __uint_as_float(((unsigned int)b) << 16);
}

typedef __attribute__((address_space(1))) unsigned int gas_u32;
typedef __attribute__((address_space(3))) unsigned int las_u32;
static __device__ __forceinline__ void gl16(const void* g, void* l) {
  __builtin_amdgcn_global_load_lds((const gas_u32*)g, (las_u32*)l, 16, 0, 0);
}

// ---------------------------------------------------------------------------
// PREP mega-kernel: 4 independent prep kernels fused into one launch.
//   role A [0,512):    key split + Vt transpose  (verified r12 body)
//   role B [512,1024): Wq+Wk split               (verified r13 body)
//   role C [1024,5776): cos table split          (verified r8 body)
//   role D [5776,7888): folded+transposed query  (verified r8 body)
// LDS: 16.5KB union (A needs [32][258] ushort; D needs [32][33] float).
// ---------------------------------------------------------------------------
__global__ __launch_bounds__(256) void prep_all(const float* __restrict__ key,
                                                unsigned short* __restrict__ keyh,
                                                unsigned short* __restrict__ keyl,
                                                unsigned short* __restrict__ Vt,
                                                const float* __restrict__ Wq,
                                                const float* __restrict__ Wk,
                                                unsigned short* __restrict__ Wqh,
                                                unsigned short* __restrict__ Wql,
                                                unsigned short* __restrict__ Wkh,
                                                unsigned short* __restrict__ Wkl,
                                                unsigned short* __restrict__ Ch,
                                                unsigned short* __restrict__ Cl,
                                                const float* __restrict__ q,
                                                unsigned short* __restrict__ Qtfh,
                                                unsigned short* __restrict__ Qtfl) {
  __shared__ __align__(16) char smem[16512];
  const int bid = blockIdx.x;
  const int t = threadIdx.x;

  if (bid < 512) {
    // ---- role A: key split + Vt transpose
    unsigned short (*lds)[258] = (unsigned short (*)[258])smem;
    const int j0 = (bid & 63) * 32;
    const int b  = bid >> 6;
#pragma unroll
    for (int p = 0; p < 32; ++p) {
      const size_t g = ((size_t)b * NK_ + j0 + p) * D_ + t;
      const float v = key[g];
      const unsigned short hb = f2bf(v);
      keyh[g] = hb;
      keyl[g] = f2bf(v - bf2f(hb));
      lds[p][t] = hb;
    }
    __syncthreads();
#pragma unroll
    for (int p = 0; p < 32; ++p) {
      const int jj = t & 31;
      const int d  = (t >> 5) + 8 * p;
      Vt[((size_t)b * D_ + d) * NK_ + j0 + jj] = lds[jj][d];
    }
  } else if (bid < 1024) {
    // ---- role B: W split (Wq then Wk)
    const int i = (bid - 512) * 256 + t;   // 0 .. 2*D*D-1
    const int n = D_ * D_;
    const float* x = (i < n) ? Wq : Wk;
    unsigned short* xh = (i < n) ? Wqh : Wkh;
    unsigned short* xl = (i < n) ? Wql : Wkl;
    const int j = (i < n) ? i : i - n;
    const float v = x[j];
    const unsigned short hb = f2bf(v);
    xh[j] = hb;
    xl[j] = f2bf(v - bf2f(hb));
  } else if (bid < 5776) {
    // ---- role C: cos table split (padded to KF_)
    const int idx = (bid - 1024) * 256 + t;   // 1152*1056 total
    const int i = idx / KF_, n = idx % KF_;
    float c = 0.f;
    if (n <= 1024) {
      const int m = (i * n) & 2047;
      c = cosf((float)m * 0.0030679615757712823f);
    }
    const unsigned short hb = f2bf(c);
    Ch[idx] = hb;
    Cl[idx] = f2bf(c - bf2f(hb));
  } else {
    // ---- role D: folded + transposed query split
    float (*lds)[33] = (float (*)[33])smem;
    const int vb = bid - 5776;              // 0..2111
    const int n0 = (vb % 33) * 32;
    const int rest = vb / 33;
    const int d0 = (rest & 7) * 32;
    const int b  = rest >> 3;
#pragma unroll
    for (int p = 0; p < 4; ++p) {
      const int idx = t + 256 * p;
      const int dd = idx & 31, nn = idx >> 5;
      const int n = n0 + nn;
      float v = 0.f;
      if (n <= 1024) v = q[((size_t)b * NQ_ + n) * D_ + d0 + dd];
      if (n >= 1 && n <= 1023) v += q[((size_t)b * NQ_ + (2048 - n)) * D_ + d0 + dd];
      lds[nn][dd] = v;
    }
    __syncthreads();
#pragma unroll
    for (int p = 0; p < 4; ++p) {
      const int idx = t + 256 * p;
      const int nn = idx & 31, dd = idx >> 5;
      const float v = lds[nn][dd];
      const unsigned short hb = f2bf(v);
      const size_t o = ((size_t)b * D_ + d0 + dd) * KF_ + n0 + nn;
      Qtfh[o] = hb;
      Qtfl[o] = f2bf(v - bf2f(hb));
    }
  }
}

// ---------------------------------------------------------------------------
// Folded DFT via split-bf16 3-MFMA. K = 1056, K-split=3 (352 = 11 steps of 32)
// with PRIVATE partial buffers + plain stores. (verified r8)
// ---------------------------------------------------------------------------
__global__ __launch_bounds__(256, 2) void dft_mfma(const unsigned short* __restrict__ Ch,
                                                   const unsigned short* __restrict__ Cl,
                                                   const unsigned short* __restrict__ Qtfh,
                                                   const unsigned short* __restrict__ Qtfl,
                                                   float* __restrict__ qr) {
  __shared__ __align__(16) unsigned short Ah[128][40];
  __shared__ __align__(16) unsigned short Al[128][40];
  __shared__ __align__(16) unsigned short Bh[128][40];
  __shared__ __align__(16) unsigned short Bl[128][40];
  const int t = threadIdx.x;
  const int b = blockIdx.z / 3, split = blockIdx.z % 3;
  const int i0 = blockIdx.x * 128, d0 = blockIdx.y * 128;
  const int w = t >> 6, lane = t & 63, quad = lane >> 4, l16 = lane & 15;
  const int wq = w & 1, wj = w >> 1;
  float* qrs = qr + (size_t)split * ((size_t)B_ * 1152 * D_);

  f32x4_t acc[4][4];
#pragma unroll
  for (int a = 0; a < 4; ++a)
#pragma unroll
    for (int c = 0; c < 4; ++c) acc[a][c] = (f32x4_t)0.f;

  const size_t abase = (size_t)i0 * KF_;
  const size_t bbase = ((size_t)b * D_ + d0) * KF_;

  for (int c0 = split * 352; c0 < split * 352 + 352; c0 += 32) {
#pragma unroll
    for (int it = 0; it < 2; ++it) {
      const int unit = t + 256 * it;           // 512 units = 128 rows x 4 slots
      const int row = unit >> 2, u = (unit & 3) * 8;
      const size_t go = (size_t)row * KF_ + c0 + u;
      *(uint4*)&Ah[row][u] = *(const uint4*)&Ch[abase + go];
      *(uint4*)&Al[row][u] = *(const uint4*)&Cl[abase + go];
      *(uint4*)&Bh[row][u] = *(const uint4*)&Qtfh[bbase + go];
      *(uint4*)&Bl[row][u] = *(const uint4*)&Qtfl[bbase + go];
    }
    __syncthreads();
    {
      const int dcol = quad * 8;
      bf16x8_t ah[4], al[4], bh[4], bl[4];
#pragma unroll
      for (int x = 0; x < 4; ++x) {
        ah[x] = *(const bf16x8_t*)&Ah[wq * 64 + x * 16 + l16][dcol];
        al[x] = *(const bf16x8_t*)&Al[wq * 64 + x * 16 + l16][dcol];
        bh[x] = *(const bf16x8_t*)&Bh[wj * 64 + x * 16 + l16][dcol];
        bl[x] = *(const bf16x8_t*)&Bl[wj * 64 + x * 16 + l16][dcol];
      }
#pragma unroll
      for (int at = 0; at < 4; ++at)
#pragma unroll
        for (int jt = 0; jt < 4; ++jt) {
          acc[at][jt] = __builtin_amdgcn_mfma_f32_16x16x32_bf16(ah[at], bh[jt], acc[at][jt], 0, 0, 0);
          acc[at][jt] = __builtin_amdgcn_mfma_f32_16x16x32_bf16(ah[at], bl[jt], acc[at][jt], 0, 0, 0);
          acc[at][jt] = __builtin_amdgcn_mfma_f32_16x16x32_bf16(al[at], bh[jt], acc[at][jt], 0, 0, 0);
        }
    }
    __syncthreads();
  }
#pragma unroll
  for (int at = 0; at < 4; ++at) {
#pragma unroll
    for (int jt = 0; jt < 4; ++jt) {
      const int d = d0 + wj * 64 + jt * 16 + l16;
#pragma unroll
      for (int r = 0; r < 4; ++r) {
        const int i = i0 + wq * 64 + at * 16 + quad * 4 + r;
        qrs[((size_t)b * 1152 + i) * D_ + d] = acc[at][jt][r];
      }
    }
  }
}

// qrh/qrl[b][i][d]: sum 3 partials; src = i<=1087 ? i : 2048-i
__global__ __launch_bounds__(256) void qr_finalize_kernel(const float* __restrict__ qr,
                                                          unsigned short* __restrict__ qrh,
                                                          unsigned short* __restrict__ qrl) {
  const int i = blockIdx.x, b = blockIdx.y, d = threadIdx.x;
  const int src = (i <= 1087) ? i : (2048 - i);
  const size_t S = (size_t)B_ * 1152 * D_;
  const size_t idx = ((size_t)b * 1152 + src) * D_ + d;
  const float v = qr[idx] + qr[idx + S] + qr[idx + 2 * S];
  const unsigned short hb = f2bf(v);
  const size_t o = ((size_t)b * NQ_ + i) * D_ + d;
  qrh[o] = hb;
  qrl[o] = f2bf(v - bf2f(hb));
}

// ---------------------------------------------------------------------------
// BATCHED projections: y = x @ W.T + bias for BOTH q and k in one launch
// (blockIdx.z selects operand set). (verified r13)
// ---------------------------------------------------------------------------
__global__ __launch_bounds__(256, 2) void proj_mfma2(
    const unsigned short* __restrict__ xh0, const unsigned short* __restrict__ xl0,
    const unsigned short* __restrict__ Wh0, const unsigned short* __restrict__ Wl0,
    const float* __restrict__ b0,
    unsigned short* __restrict__ yh0, unsigned short* __restrict__ yl0,
    const unsigned short* __restrict__ xh1, const unsigned short* __restrict__ xl1,
    const unsigned short* __restrict__ Wh1, const unsigned short* __restrict__ Wl1,
    const float* __restrict__ b1,
    unsigned short* __restrict__ yh1, unsigned short* __restrict__ yl1) {
  const int z = blockIdx.z;
  const unsigned short* xh = z ? xh1 : xh0;
  const unsigned short* xl = z ? xl1 : xl0;
  const unsigned short* Wh = z ? Wh1 : Wh0;
  const unsigned short* Wl = z ? Wl1 : Wl0;
  const float* bias = z ? b1 : b0;
  unsigned short* yh = z ? yh1 : yh0;
  unsigned short* yl = z ? yl1 : yl0;

  __shared__ __align__(16) unsigned short Xh[128][72];
  __shared__ __align__(16) unsigned short Xl[128][72];
  __shared__ __align__(16) unsigned short Bh[128][72];
  __shared__ __align__(16) unsigned short Bl[128][72];
  const int t = threadIdx.x;
  const int m0 = blockIdx.x * 128, o0 = blockIdx.y * 128;
  const int w = t >> 6, lane = t & 63, quad = lane >> 4, l16 = lane & 15;
  const int wq = w & 1, wj = w >> 1;

  f32x4_t acc[4][4];
#pragma unroll
  for (int a = 0; a < 4; ++a)
#pragma unroll
    for (int c = 0; c < 4; ++c) acc[a][c] = (f32x4_t)0.f;

  const size_t xbase = (size_t)m0 * D_;
  const size_t wbase = (size_t)o0 * D_;

  for (int c0 = 0; c0 < D_; c0 += 64) {
#pragma unroll
    for (int it = 0; it < 4; ++it) {
      const int unit = t + 256 * it;
      const int row = unit >> 3, u = (unit & 7) * 8;
      const size_t go = (size_t)row * D_ + c0 + u;
      *(uint4*)&Xh[row][u] = *(const uint4*)&xh[xbase + go];
      *(uint4*)&Xl[row][u] = *(const uint4*)&xl[xbase + go];
      *(uint4*)&Bh[row][u] = *(const uint4*)&Wh[wbase + go];
      *(uint4*)&Bl[row][u] = *(const uint4*)&Wl[wbase + go];
    }
    __syncthreads();
#pragma unroll
    for (int ks = 0; ks < 2; ++ks) {
      const int dcol = ks * 32 + quad * 8;
      bf16x8_t ah[4], al[4], bh[4], bl[4];
#pragma unroll
      for (int x = 0; x < 4; ++x) {
        ah[x] = *(const bf16x8_t*)&Xh[wq * 64 + x * 16 + l16][dcol];
        al[x] = *(const bf16x8_t*)&Xl[wq * 64 + x * 16 + l16][dcol];
        bh[x] = *(const bf16x8_t*)&Bh[wj * 64 + x * 16 + l16][dcol];
        bl[x] = *(const bf16x8_t*)&Bl[wj * 64 + x * 16 + l16][dcol];
      }
#pragma unroll
      for (int at = 0; at < 4; ++at)
#pragma unroll
        for (int jt = 0; jt < 4; ++jt) {
          acc[at][jt] = __builtin_amdgcn_mfma_f32_16x16x32_bf16(ah[at], bh[jt], acc[at][jt], 0, 0, 0);
          acc[at][jt] = __builtin_amdgcn_mfma_f32_16x16x32_bf16(ah[at], bl[jt], acc[at][jt], 0, 0, 0);
          acc[at][jt] = __builtin_amdgcn_mfma_f32_16x16x32_bf16(al[at], bh[jt], acc[at][jt], 0, 0, 0);
        }
    }
    __syncthreads();
  }
#pragma unroll
  for (int at = 0; at < 4; ++at) {
#pragma unroll
    for (int jt = 0; jt < 4; ++jt) {
      const int o = o0 + wj * 64 + jt * 16 + l16;
      const float bv = bias[o];
#pragma unroll
      for (int r = 0; r < 4; ++r) {
        const int m = m0 + wq * 64 + at * 16 + quad * 4 + r;
        const float v = acc[at][jt][r] + bv;
        const unsigned short hb = f2bf(v);
        yh[(size_t)m * D_ + o] = hb;
        yl[(size_t)m * D_ + o] = f2bf(v - bf2f(hb));
      }
    }
  }
}

// ---------------------------------------------------------------------------
// scores + per-jblock softmax stats. 8-wave, BK=64 SINGLE-BUFFER m97-style
// (verified r9). 66KB LDS keeps 2 blocks/CU (16 waves). XOR swizzle:
// slot ^ (row&7). Pb TILED: Pb[(b*16+jb)][i][128]. ln2 offsets.
// ---------------------------------------------------------------------------
__global__ __launch_bounds__(512, 4) void scores_p(const unsigned short* __restrict__ qh,
                                                   const unsigned short* __restrict__ ql,
                                                   const unsigned short* __restrict__ kh,
                                                   const unsigned short* __restrict__ kl,
                                                   unsigned short* __restrict__ Pb,
                                                   float2* __restrict__ stat) {
  __shared__ __align__(16) unsigned short Qh[128][64];
  __shared__ __align__(16) unsigned short Ql[128][64];
  __shared__ __align__(16) unsigned short Kh[128][64];
  __shared__ __align__(16) unsigned short Kl[128][64];
  __shared__ float mred[2][128];
  __shared__ float lred[2][128];
  const int t = threadIdx.x;
  const int b = blockIdx.z;
  const int i0 = blockIdx.x * 128, j0 = blockIdx.y * 128;
  const int jb = blockIdx.y;   // 0..15
  const int w = t >> 6, lane = t & 63, quad = lane >> 4, l16 = lane & 15;
  const int wq = w & 3, wj = w >> 2;         // 4 row-groups x 2 col-groups
  const int sr0 = t >> 3, ssl = t & 7;       // staging: row 0..63, 16B slot 0..7

  f32x4_t acc[2][4];
#pragma unroll
  for (int x = 0; x < 2; ++x)
#pragma unroll
    for (int y = 0; y < 4; ++y) acc[x][y] = (f32x4_t)0.f;

  const size_t qbase = ((size_t)b * NQ_ + i0) * D_;
  const size_t kbase = ((size_t)b * NK_ + j0) * D_;

  auto STAGE = [&](int c0) {
#pragma unroll
    for (int half = 0; half < 2; ++half) {
      const int row = half * 64 + sr0;
      const int sg = (ssl ^ (row & 7)) * 8;
      const size_t ro = (size_t)row * D_ + c0 + sg;
      gl16(qh + qbase + ro, &Qh[half * 64 + w * 8][0]);
      gl16(ql + qbase + ro, &Ql[half * 64 + w * 8][0]);
      gl16(kh + kbase + ro, &Kh[half * 64 + w * 8][0]);
      gl16(kl + kbase + ro, &Kl[half * 64 + w * 8][0]);
    }
  };

  STAGE(0);   // prologue

#pragma unroll
  for (int s = 0; s < 4; ++s) {
    asm volatile("s_waitcnt vmcnt(0)" ::: "memory");   // tile s staged
    __builtin_amdgcn_s_barrier();
    asm volatile("" ::: "memory");

#pragma unroll
    for (int ks = 0; ks < 2; ++ks) {
      bf16x8_t ah[2], al[2], bh[4], bl[4];
#pragma unroll
      for (int x = 0; x < 2; ++x) {
        const int ar = wq * 32 + x * 16 + l16;
        const int asl = ((ks * 4 + quad) ^ (ar & 7)) * 8;
        ah[x] = *(const bf16x8_t*)&Qh[ar][asl];
        al[x] = *(const bf16x8_t*)&Ql[ar][asl];
      }
#pragma unroll
      for (int y = 0; y < 4; ++y) {
        const int br = wj * 64 + y * 16 + l16;
        const int bsl = ((ks * 4 + quad) ^ (br & 7)) * 8;
        bh[y] = *(const bf16x8_t*)&Kh[br][bsl];
        bl[y] = *(const bf16x8_t*)&Kl[br][bsl];
      }
#pragma unroll
      for (int x = 0; x < 2; ++x)
#pragma unroll
        for (int y = 0; y < 4; ++y) {
          acc[x][y] = __builtin_amdgcn_mfma_f32_16x16x32_bf16(ah[x], bh[y], acc[x][y], 0, 0, 0);
          acc[x][y] = __builtin_amdgcn_mfma_f32_16x16x32_bf16(ah[x], bl[y], acc[x][y], 0, 0, 0);
          acc[x][y] = __builtin_amdgcn_mfma_f32_16x16x32_bf16(al[x], bh[y], acc[x][y], 0, 0, 0);
        }
    }

    asm volatile("" ::: "memory");
    __builtin_amdgcn_s_barrier();
    asm volatile("" ::: "memory");
    if (s < 3) STAGE((s + 1) * 64);                    // overwrite buffer
  }

  // --- epilogue: per-row (over this block's 128 j) max, exp, sum, bf16 store
  const float scale = 0.0625f;
  float mt[2][4];
#pragma unroll
  for (int x = 0; x < 2; ++x)
#pragma unroll
    for (int r = 0; r < 4; ++r) mt[x][r] = -3e38f;
#pragma unroll
  for (int x = 0; x < 2; ++x)
#pragma unroll
    for (int y = 0; y < 4; ++y)
#pragma unroll
      for (int r = 0; r < 4; ++r) {
        acc[x][y][r] *= scale;
        mt[x][r] = fmaxf(mt[x][r], acc[x][y][r]);
      }
#pragma unroll
  for (int off = 1; off < 16; off <<= 1)
#pragma unroll
    for (int x = 0; x < 2; ++x)
#pragma unroll
      for (int r = 0; r < 4; ++r) mt[x][r] = fmaxf(mt[x][r], __shfl_xor(mt[x][r], off));
  if (l16 == 0) {
#pragma unroll
    for (int x = 0; x < 2; ++x)
#pragma unroll
      for (int r = 0; r < 4; ++r)
        mred[wj][wq * 32 + x * 16 + quad * 4 + r] = mt[x][r];
  }
  __syncthreads();
  float nrow[2][4], mu[2][4], lt[2][4];
#pragma unroll
  for (int x = 0; x < 2; ++x)
#pragma unroll
    for (int r = 0; r < 4; ++r) {
      const int rr = wq * 32 + x * 16 + quad * 4 + r;
      const float m = fmaxf(mred[0][rr], mred[1][rr]);
      const float n = ceilf(m * 1.44269504f);       // ln2 grid
      nrow[x][r] = n;
      mu[x][r] = n * 0.69314718056f;
      lt[x][r] = 0.f;
    }
  const size_t pbase = ((size_t)(b * 16 + jb)) * NQ_ * 128;
#pragma unroll
  for (int x = 0; x < 2; ++x)
#pragma unroll
    for (int y = 0; y < 4; ++y) {
      const int jloc = wj * 64 + y * 16 + l16;      // 0..127 within tile
#pragma unroll
      for (int r = 0; r < 4; ++r) {
        const int i = i0 + wq * 32 + x * 16 + quad * 4 + r;
        float p = __expf(acc[x][y][r] - mu[x][r]);
        p = fmaxf(p, 8.673617e-19f);                // clamp >= 2^-60 (no bf16 zeros)
        lt[x][r] += p;
        Pb[pbase + (size_t)i * 128 + jloc] = f2bf(p);
      }
    }
#pragma unroll
  for (int off = 1; off < 16; off <<= 1)
#pragma unroll
    for (int x = 0; x < 2; ++x)
#pragma unroll
      for (int r = 0; r < 4; ++r) lt[x][r] += __shfl_xor(lt[x][r], off);
  if (l16 == 0) {
#pragma unroll
    for (int x = 0; x < 2; ++x)
#pragma unroll
      for (int r = 0; r < 4; ++r)
        lred[wj][wq * 32 + x * 16 + quad * 4 + r] = lt[x][r];
  }
  __syncthreads();
  if (wj == 0 && l16 == 0) {
#pragma unroll
    for (int x = 0; x < 2; ++x)
#pragma unroll
      for (int r = 0; r < 4; ++r) {
        const int rr = wq * 32 + x * 16 + quad * 4 + r;
        stat[(size_t)jb * (B_ * NQ_) + (size_t)b * NQ_ + i0 + rr] =
            make_float2(nrow[x][r], lred[0][rr] + lred[1][rr]);
      }
  }
}

// ---------------------------------------------------------------------------
// out[m,d] = (1/l) * sum_{all j} P[m,j]*2^(n_jb-n_max) * V[j,d]
// ATOMIC-FREE (verified r6) + ROWFIN FOLDED IN: per-row n_max and 1/l are
// computed inline from the 16 jb stats (numerically identical to the old
// rowfin kernel); epilogue gets 1/l via __shfl broadcast.
// 256 blocks (1/CU), 512 threads, 64-wide j-steps, triple-buffered depth-2
// gl16 pipeline (vmcnt(10)), XCD-remap for V L2 residency.
// ---------------------------------------------------------------------------
__global__ __launch_bounds__(512, 1) void pv_p(const unsigned short* __restrict__ Pb,
                                               const float2* __restrict__ stat,
                                               const unsigned short* __restrict__ Vt,
                                               float* __restrict__ out) {
  __shared__ __align__(16) unsigned short Ps[3][64][64];
  __shared__ __align__(16) unsigned short Vs[3][256][64];
  const int t = threadIdx.x;
  const int lb = (blockIdx.x & 7) * 32 + (blockIdx.x >> 3);
  const int mb = lb * 64;                    // flattened row base (b*NQ + i)
  const int b  = lb >> 5;                    // batch (32 blocks per batch)
  const int i0 = mb & (NQ_ - 1);             // row within batch
  const int w = t >> 6, lane = t & 63, quad = lane >> 4, l16 = lane & 15;
  const int wm = w & 1, wd = w >> 1;         // wave: row-half (32), d-quarter (64)
  const int prow = t >> 3, pslot = t & 7;    // staging: row, 16B slot

  // ---- per-row stats (folded rowfin): n_max, 1/l, exponent corrections
  unsigned int es2[16][2];
  float linv[2];
#pragma unroll
  for (int x = 0; x < 2; ++x) {
    const int arow = mb + wm * 32 + x * 16 + l16;
    float2 st[16];
    float m = -3e38f;
#pragma unroll
    for (int jb = 0; jb < 16; ++jb) {
      st[jb] = stat[(size_t)jb * (B_ * NQ_) + arow];
      m = fmaxf(m, st[jb].x);
    }
    float l = 0.f;
#pragma unroll
    for (int jb = 0; jb < 16; ++jb) {
      l += st[jb].y * exp2f(st[jb].x - m);
      int e = (int)(m - st[jb].x);
      e = e < 0 ? 0 : (e > 60 ? 60 : e);
      es2[jb][x] = (unsigned int)(e << 7) * 0x00010001u;
    }
    linv[x] = 1.0f / l;
  }

  f32x4_t acc[2][4];
#pragma unroll
  for (int x = 0; x < 2; ++x)
#pragma unroll
    for (int y = 0; y < 4; ++y) acc[x][y] = (f32x4_t)0.f;

  const size_t vbase = (size_t)b * D_ * (size_t)NK_;

  auto STAGE = [&](int nb, int s) {
    const int jj = s * 64;
    const int jb = jj >> 7, off = jj & 127;
    {  // P: 1 gl16/thread
      const int sg = pslot ^ (prow & 7);
      gl16(Pb + ((size_t)(b * 16 + jb)) * NQ_ * 128 +
               (size_t)(i0 + prow) * 128 + off + sg * 8,
           &Ps[nb][w * 8][0]);
    }
#pragma unroll
    for (int k = 0; k < 4; ++k) {  // V: 4 gl16/thread
      const int vrow = k * 64 + prow;
      const int sg = pslot ^ (vrow & 7);
      gl16(Vt + vbase + (size_t)vrow * NK_ + jj + sg * 8,
           &Vs[nb][k * 64 + w * 8][0]);
    }
  };

  asm volatile("s_waitcnt vmcnt(0)" ::: "memory");  // drain stat loads
  STAGE(0, 0);
  STAGE(1, 1);

#pragma unroll
  for (int s = 0; s < 32; ++s) {
    const int cb = s % 3;
    if (s < 30) {
      STAGE((s + 2) % 3, s + 2);                        // depth-2 prefetch
      asm volatile("s_waitcnt vmcnt(10)" ::: "memory"); // step s ready
    } else if (s == 30) {
      asm volatile("s_waitcnt vmcnt(5)" ::: "memory");
    } else {
      asm volatile("s_waitcnt vmcnt(0)" ::: "memory");
    }
    __builtin_amdgcn_s_barrier();
    asm volatile("" ::: "memory");

    const unsigned int e0 = es2[s >> 1][0], e1 = es2[s >> 1][1];
#pragma unroll
    for (int ks = 0; ks < 2; ++ks) {
      bf16x8_t a[2], bv[4];
#pragma unroll
      for (int x = 0; x < 2; ++x) {
        const int row = wm * 32 + x * 16 + l16;
        const int sk = (ks * 4 + quad) ^ (row & 7);
        uint4 u = *(const uint4*)&Ps[cb][row][sk * 8];
        const unsigned int e = (x == 0) ? e0 : e1;
        u.x -= e; u.y -= e; u.z -= e; u.w -= e;
        a[x] = *(const bf16x8_t*)&u;                 // P * 2^(n_jb - n_max)
      }
#pragma unroll
      for (int y = 0; y < 4; ++y) {
        const int row = wd * 64 + y * 16 + l16;
        const int sk = (ks * 4 + quad) ^ (row & 7);
        bv[y] = *(const bf16x8_t*)&Vs[cb][row][sk * 8];
      }
#pragma unroll
      for (int x = 0; x < 2; ++x)
#pragma unroll
        for (int y = 0; y < 4; ++y)
          acc[x][y] = __builtin_amdgcn_mfma_f32_16x16x32_bf16(a[x], bv[y], acc[x][y], 0, 0, 0);
    }

    asm volatile("" ::: "memory");
    __builtin_amdgcn_s_barrier();
    asm volatile("" ::: "memory");
  }

  // epilogue: 1/l broadcast from the lane holding that row (l16 == quad*4+r)
#pragma unroll
  for (int x = 0; x < 2; ++x) {
    float sy[4];
#pragma unroll
    for (int r = 0; r < 4; ++r)
      sy[r] = __shfl(linv[x], quad * 4 + r);
#pragma unroll
    for (int y = 0; y < 4; ++y) {
      const int d = wd * 64 + y * 16 + l16;
#pragma unroll
      for (int r = 0; r < 4; ++r) {
        const int m = mb + wm * 32 + x * 16 + quad * 4 + r;
        out[(size_t)m * D_ + d] = acc[x][y][r] * sy[r];
      }
    }
  }
}

extern "C" void kernel_launch(void* const* d_in, const int* in_sizes, int n_in,
                              void* d_out, int out_size, void* d_ws, size_t ws_size,
                              hipStream_t stream) {
  const float* query = (const float*)d_in[0];
  const float* key   = (const float*)d_in[1];
  const float* Wq    = (const float*)d_in[2];
  const float* bq    = (const float*)d_in[3];
  const float* Wk    = (const float*)d_in[4];
  const float* bk    = (const float*)d_in[5];
  float* out = (float*)d_out;

  char* ws = (char*)d_ws;
  const size_t MB = (size_t)1 << 20;
  // persistent:
  unsigned short* qh = (unsigned short*)(ws);             // 8 MB
  unsigned short* ql = (unsigned short*)(ws + 8 * MB);
  unsigned short* kh = (unsigned short*)(ws + 16 * MB);
  unsigned short* kl = (unsigned short*)(ws + 24 * MB);
  unsigned short* Vt = (unsigned short*)(ws + 32 * MB);
  unsigned short* Pb = (unsigned short*)(ws + 40 * MB);   // 64 MB (tiled [b*16+jb][2048][128])
  float2* stat = (float2*)(ws + 108 * MB);                // 2 MB
  // transients (all dead before scores_p writes Pb):
  unsigned short* Ch   = (unsigned short*)(ws + 40 * MB);   // 2.43 MB (1152x1056)
  unsigned short* Cl   = (unsigned short*)(ws + 43 * MB);   // 2.43 MB
  unsigned short* Qtfh = (unsigned short*)(ws + 46 * MB);   // 4.33 MB (8x256x1056)
  unsigned short* Qtfl = (unsigned short*)(ws + 51 * MB);   // 4.33 MB
  float*          qr   = (float*)(ws + 56 * MB);            // 3 x 9.44 MB partials (56,66,76)
  unsigned short* qrh  = (unsigned short*)(ws + 40 * MB);   // 8 MB (overlays dead C'/Qtf)
  unsigned short* qrl  = (unsigned short*)(ws + 48 * MB);   // 8 MB (ends 56, before qr partials)
  unsigned short* keyh = (unsigned short*)(ws + 92 * MB);   // 8 MB
  unsigned short* keyl = (unsigned short*)(ws + 100 * MB);  // 8 MB
  unsigned short* Wqh  = (unsigned short*)(ws + 111 * MB);  // 128 KB
  unsigned short* Wql  = (unsigned short*)(ws + 111 * MB + 256 * 1024);
  unsigned short* Wkh  = (unsigned short*)(ws + 111 * MB + 512 * 1024);
  unsigned short* Wkl  = (unsigned short*)(ws + 111 * MB + 768 * 1024);

  dim3 blk(256);

  // all prep work in one launch (key split+Vt, W splits, cos table, q fold)
  prep_all<<<7888, blk, 0, stream>>>(key, keyh, keyl, Vt, Wq, Wk,
                                     Wqh, Wql, Wkh, Wkl, Ch, Cl,
                                     query, Qtfh, Qtfl);
  // folded DFT: K=1056, 3-way K-split into private partial buffers
  dft_mfma<<<dim3(9, 2, B_ * 3), blk, 0, stream>>>(Ch, Cl, Qtfh, Qtfl, qr);
  qr_finalize_kernel<<<dim3(2048, B_), blk, 0, stream>>>(qr, qrh, qrl);
  // batched projections (q and k in one launch, 2 blocks/CU)
  proj_mfma2<<<dim3(B_ * NQ_ / 128, 2, 2), blk, 0, stream>>>(
      qrh, qrl, Wqh, Wql, bq, qh, ql,
      keyh, keyl, Wkh, Wkl, bk, kh, kl);
  // attention: scores (bf16 P + per-jb pow2 stats) -> PV (rowfin folded in)
  scores_p<<<dim3(NQ_ / 128, NK_ / 128, B_), dim3(512), 0, stream>>>(qh, ql, kh, kl, Pb, stat);
  pv_p<<<dim3(256), dim3(512), 0, stream>>>(Pb, stat, Vt, out);
}